// Round 5
// baseline (591.796 us; speedup 1.0000x reference)
//
#include <hip/hip_runtime.h>
#include <hip/hip_cooperative_groups.h>

// HoloGraphBlockV7 — round 5: single cooperative mega-kernel (10 grid.sync()s)
// + 3-stage GEMM software pipeline + fully parallel cross-chunk scan combine.
// Dispatches: prep(+LN1) -> mega. 13 -> 2.

namespace cg = cooperative_groups;

typedef unsigned short u16;
typedef unsigned int u32;
typedef __attribute__((ext_vector_type(8))) short short8;
typedef __attribute__((ext_vector_type(4))) float floatx4;

__device__ __forceinline__ float b2f(u16 u) {
  u32 x = ((u32)u) << 16;
  return __uint_as_float(x);
}
__device__ __forceinline__ u16 f2b(float f) {
  u32 x = __float_as_uint(f);
  u32 r = (x + 0x7fffu + ((x >> 16) & 1u)) >> 16;
  return (u16)r;
}
__device__ __forceinline__ float4 b4_to_f4(uint2 u) {
  float4 r;
  r.x = __uint_as_float((u.x & 0xffffu) << 16);
  r.y = __uint_as_float(u.x & 0xffff0000u);
  r.z = __uint_as_float((u.y & 0xffffu) << 16);
  r.w = __uint_as_float(u.y & 0xffff0000u);
  return r;
}

__device__ __forceinline__ void stage16(const u16* g, u16* lds_wave_base) {
  __builtin_amdgcn_global_load_lds((const __attribute__((address_space(1))) void*)g,
                                   (__attribute__((address_space(3))) void*)lds_wave_base,
                                   16, 0, 0);
}

// Stage a ROWSx32 bf16 tile (k-block kb) into LDS [row][32] with k-quad XOR
// swizzle: LDS(row, c) holds global k-quad c ^ ((row>>1)&3).
template <int ROWS>
__device__ __forceinline__ void stage_tile(const u16* __restrict__ G, int ldK, int kb,
                                           u16* lds, int tid) {
#pragma unroll
  for (int r = 0; r < ROWS / 64; ++r) {
    int slot = r * 256 + tid;
    int row = slot >> 2;
    int kwg = (slot & 3) ^ ((row >> 1) & 3);
    stage16(G + (size_t)row * ldK + kb * 32 + kwg * 8,
            lds + (size_t)(r * 256 + (tid >> 6) * 64) * 8);
  }
}

// ---------------------------------------------------------------------------
// 3-stage-pipelined bf16 MFMA GEMM phase (device function; runs inside mega).
// EPI 0: outf = v;  1: outf = aux0+v+0.1*aux1;  2: outb = bf16(gelu(v));
// 3: w=aux0+v, outf=w, outb=bf16(w);  4: outf=aux0+v, outf2=aux1+v.
template <int BM, int BN, int EPI>
__device__ __forceinline__ void gemm_phase(
    int bid, int tid, char* smem,
    const u16* __restrict__ A, const u16* __restrict__ BT, const float* __restrict__ bias,
    float* __restrict__ outf, float* __restrict__ outf2, u16* __restrict__ outb,
    const float* __restrict__ aux0, const float* __restrict__ aux1, int M, int N, int K) {
  constexpr int MT = BM / 32, NT = BN / 32;
  constexpr int S = BM / 64 + BN / 64;  // DMA insts per thread per tile
  const int tiles_x = N / BN;
  const int n_tiles = (M / BM) * tiles_x;
  if (bid >= n_tiles) return;
  u16* As = (u16*)smem;            // 3 buffers of BM*32
  u16* Bs = As + 3 * BM * 32;      // 3 buffers of BN*32
  const int lane = tid & 63, wave = tid >> 6;
  const int wm = wave >> 1, wn = wave & 1;
  const int m0 = (bid / tiles_x) * BM, n0 = (bid % tiles_x) * BN;
  floatx4 acc[MT][NT] = {};
  const int fr = lane & 15, kq = lane >> 4;
  const int nk = K >> 5;
  const u16* Ab = A + (size_t)m0 * K;
  const u16* Bb = BT + (size_t)n0 * K;

  stage_tile<BM>(Ab, K, 0, As, tid);
  stage_tile<BN>(Bb, K, 0, Bs, tid);
  if (nk > 1) {
    stage_tile<BM>(Ab, K, 1, As + BM * 32, tid);
    stage_tile<BN>(Bb, K, 1, Bs + BN * 32, tid);
  }

  for (int kb = 0; kb < nk; ++kb) {
    const int cur = kb % 3;
    if (kb + 2 < nk) {
      const int nxt = (kb + 2) % 3;
      stage_tile<BM>(Ab, K, kb + 2, As + nxt * BM * 32, tid);
      stage_tile<BN>(Bb, K, kb + 2, Bs + nxt * BN * 32, tid);
    }
    int ahead = nk - 1 - kb;
    if (ahead > 2) ahead = 2;
    if constexpr (S == 4) {
      if (ahead == 2) asm volatile("s_waitcnt vmcnt(8)" ::: "memory");
      else if (ahead == 1) asm volatile("s_waitcnt vmcnt(4)" ::: "memory");
      else asm volatile("s_waitcnt vmcnt(0)" ::: "memory");
    } else {
      if (ahead == 2) asm volatile("s_waitcnt vmcnt(4)" ::: "memory");
      else if (ahead == 1) asm volatile("s_waitcnt vmcnt(2)" ::: "memory");
      else asm volatile("s_waitcnt vmcnt(0)" ::: "memory");
    }
    asm volatile("s_barrier" ::: "memory");

    const u16* Ac = As + cur * BM * 32;
    const u16* Bc = Bs + cur * BN * 32;
    short8 af[MT], bf[NT];
#pragma unroll
    for (int mt = 0; mt < MT; ++mt) {
      int row = wm * (BM / 2) + mt * 16 + fr;
      af[mt] = *(const short8*)&Ac[row * 32 + (kq ^ ((row >> 1) & 3)) * 8];
    }
#pragma unroll
    for (int nt = 0; nt < NT; ++nt) {
      int row = wn * (BN / 2) + nt * 16 + fr;
      bf[nt] = *(const short8*)&Bc[row * 32 + (kq ^ ((row >> 1) & 3)) * 8];
    }
#pragma unroll
    for (int mt = 0; mt < MT; ++mt)
#pragma unroll
      for (int nt = 0; nt < NT; ++nt)
        acc[mt][nt] =
            __builtin_amdgcn_mfma_f32_16x16x32_bf16(af[mt], bf[nt], acc[mt][nt], 0, 0, 0);
    asm volatile("s_waitcnt lgkmcnt(0)" ::: "memory");
    asm volatile("s_barrier" ::: "memory");
  }

  const int col = lane & 15;
  const int rbase = (lane >> 4) * 4;
#pragma unroll
  for (int nt = 0; nt < NT; ++nt) {
    int gc = n0 + wn * (BN / 2) + nt * 16 + col;
    float bvv = bias[gc];
#pragma unroll
    for (int mt = 0; mt < MT; ++mt) {
      int gr = m0 + wm * (BM / 2) + mt * 16 + rbase;
#pragma unroll
      for (int r = 0; r < 4; ++r) {
        size_t idx = (size_t)(gr + r) * N + gc;
        float v = acc[mt][nt][r] + bvv;
        if constexpr (EPI == 0) {
          outf[idx] = v;
        } else if constexpr (EPI == 1) {
          outf[idx] = aux0[idx] + v + 0.1f * aux1[idx];
        } else if constexpr (EPI == 2) {
          outb[idx] = f2b(0.5f * v * (1.f + erff(v * 0.70710678118654752f)));
        } else if constexpr (EPI == 3) {
          float w = aux0[idx] + v;
          outf[idx] = w;
          outb[idx] = f2b(w);
        } else {
          outf[idx] = aux0[idx] + v;
          outf2[idx] = aux1[idx] + v;
        }
      }
    }
  }
}

// LayerNorm of one 512-row; 256 threads; red = 8 floats in smem.
__device__ __forceinline__ void ln_row(const float* __restrict__ xr,
                                       const float* __restrict__ g,
                                       const float* __restrict__ bt,
                                       u16* __restrict__ yr, int tid, float* red) {
  float x0 = xr[tid], x1 = xr[tid + 256];
  float s = x0 + x1, ss = x0 * x0 + x1 * x1;
#pragma unroll
  for (int o = 32; o > 0; o >>= 1) { s += __shfl_xor(s, o); ss += __shfl_xor(ss, o); }
  if ((tid & 63) == 0) { red[tid >> 6] = s; red[4 + (tid >> 6)] = ss; }
  __syncthreads();
  float ts = red[0] + red[1] + red[2] + red[3];
  float tss = red[4] + red[5] + red[6] + red[7];
  float mu = ts * (1.f / 512.f);
  float var = tss * (1.f / 512.f) - mu * mu;
  float rstd = 1.0f / sqrtf(var + 1e-5f);
  yr[tid] = f2b((x0 - mu) * rstd * g[tid] + bt[tid]);
  yr[tid + 256] = f2b((x1 - mu) * rstd * g[tid + 256] + bt[tid + 256]);
  __syncthreads();
}

// ---------------------------------------------------------------------------
// Prep kernel: weight transposes f32->bf16 (blocks 0..3327), gate/bias pack
// (3328..3391), LN1 rows (3392..5439) — all independent of each other.
__global__ __launch_bounds__(256) void prep_weights(
    const float* __restrict__ Wk, const float* __restrict__ Wq,
    const float* __restrict__ Wv, const float* __restrict__ Wo,
    const float* __restrict__ Wps, const float* __restrict__ W1,
    const float* __restrict__ W2, const float* __restrict__ Wd,
    const float* __restrict__ Wgw, const float* __restrict__ Wgf,
    const float* __restrict__ bk, const float* __restrict__ bq,
    const float* __restrict__ bv, const float* __restrict__ bd,
    const float* __restrict__ bgw, const float* __restrict__ bgf,
    const float* __restrict__ x, const float* __restrict__ ln1g,
    const float* __restrict__ ln1b,
    u16* __restrict__ WTQ, u16* __restrict__ WTO, u16* __restrict__ WTPS,
    u16* __restrict__ WT1, u16* __restrict__ WT2, float* __restrict__ BQV,
    u16* __restrict__ XN) {
  int bid = blockIdx.x, tid = threadIdx.x;
  __shared__ float tile[32][33];
  __shared__ float red[8];
  if (bid < 3328) {
    const float* src;
    u16* dst;
    int C, rel, tiles_x;
    if (bid < 256)       { src = Wk;  dst = WTQ;           C = 512;  rel = bid;        tiles_x = 16; }
    else if (bid < 512)  { src = Wq;  dst = WTQ + 262144;  C = 512;  rel = bid - 256;  tiles_x = 16; }
    else if (bid < 768)  { src = Wv;  dst = WTQ + 524288;  C = 512;  rel = bid - 512;  tiles_x = 16; }
    else if (bid < 1024) { src = Wo;  dst = WTO;           C = 512;  rel = bid - 768;  tiles_x = 16; }
    else if (bid < 1280) { src = Wps; dst = WTPS;          C = 512;  rel = bid - 1024; tiles_x = 16; }
    else if (bid < 2304) { src = W1;  dst = WT1;           C = 2048; rel = bid - 1280; tiles_x = 64; }
    else                 { src = W2;  dst = WT2;           C = 512;  rel = bid - 2304; tiles_x = 16; }
    int R = (bid >= 1280 && bid < 2304) ? 512 : (bid >= 2304 ? 2048 : 512);
    int c0 = (rel % tiles_x) * 32, r0 = (rel / tiles_x) * 32;
    int tx = tid & 31, ty = tid >> 5;
#pragma unroll
    for (int i = 0; i < 4; ++i)
      tile[ty + i * 8][tx] = src[(size_t)(r0 + ty + i * 8) * C + c0 + tx];
    __syncthreads();
#pragma unroll
    for (int i = 0; i < 4; ++i)
      dst[(size_t)(c0 + ty + i * 8) * R + r0 + tx] = f2b(tile[tx][ty + i * 8]);
  } else if (bid < 3392) {
    int idx = (bid - 3328) * 256 + tid;
    const int stride = 64 * 256;
    for (int i = idx; i < 128 * 512; i += stride) {
      int local = i >> 9, k = i & 511;
      float v = 0.f;
      if (local < 8) v = Wd[k * 8 + local];
      else if (local < 16) v = Wgw[k * 8 + (local - 8)];
      else if (local < 24) v = Wgf[k * 8 + (local - 16)];
      WTQ[(size_t)(1536 + local) * 512 + k] = f2b(v);
    }
    for (int i = idx; i < 1664; i += stride) {
      float v = 0.f;
      if (i < 512) v = bk[i];
      else if (i < 1024) v = bq[i - 512];
      else if (i < 1536) v = bv[i - 1024];
      else if (i < 1544) v = bd[i - 1536];
      else if (i < 1552) v = bgw[i - 1544];
      else if (i < 1560) v = bgf[i - 1552];
      BQV[i] = v;
    }
  } else {
    int row = bid - 3392;
    ln_row(x + (size_t)row * 512, ln1g, ln1b, XN + (size_t)row * 512, tid, red);
  }
}

// ---------------------------------------------------------------------------
struct MP {
  const float *x, *bmin, *bmax, *motif;
  const float *bo, *b1, *b2, *bps, *ln2g, *ln2b;
  const u16 *WTQ, *WTO, *WT1, *WT2, *WTPS, *XN;
  const float *BQV;
  float* C0;
  u16 *KB, *QB, *VG;
  float *DEC, *LC, *WW, *RP, *SF, *SI;
  u16 *AB, *HB, *MID, *X3B;
  float* X2;
  float *out0, *out1, *out2, *out3;
};

__global__ __launch_bounds__(256) void mega(MP p) {
  __shared__ __align__(16) char smem[49664];
  const int bid = blockIdx.x, tid = threadIdx.x;
  cg::grid_group grid = cg::this_grid();

  // P1: QKV+gates GEMM (13x16 tiles)
  gemm_phase<128, 128, 0>(bid, tid, smem, p.XN, p.WTQ, p.BQV, p.C0, nullptr, nullptr,
                          nullptr, nullptr, 2048, 1664, 512);
  grid.sync();

  // P2: per-token epilogue (8 tokens/block, 4 heads per pass)
  {
    int d = tid & 63;
    for (int tt = 0; tt < 8; ++tt) {
      int tok = bid * 8 + tt;
      int b = tok >> 10, t = tok & 1023;
      const float* row = p.C0 + (size_t)tok * 1664;
#pragma unroll
      for (int pass = 0; pass < 2; ++pass) {
        int h = (tid >> 6) + pass * 4;
        float dl = row[1536 + h], gwl = row[1544 + h], gfl = row[1552 + h];
        float dd = dl > 20.f ? dl : log1pf(expf(dl));
        float sw = 1.f / (1.f + expf(-gwl));
        float gw = sw * sw;
        float sf = 1.f / (1.f + expf(-gfl));
        float gf = 1.f - sf * sf;
        size_t obase = ((size_t)(b * 8 + h) * 1024 + t) * 64 + d;
        float kx = row[h * 64 + d];
        float ssk = kx * kx;
#pragma unroll
        for (int o = 32; o > 0; o >>= 1) ssk += __shfl_xor(ssk, o);
        p.KB[obase] = f2b(kx / fmaxf(sqrtf(ssk), 1e-12f));
        float qx = row[512 + h * 64 + d];
        float ssq = qx * qx;
#pragma unroll
        for (int o = 32; o > 0; o >>= 1) ssq += __shfl_xor(ssq, o);
        p.QB[obase] = f2b(qx / fmaxf(sqrtf(ssq), 1e-12f));
        float vx = tanhf(row[1024 + h * 64 + d]);
        p.VG[obase] = f2b(vx * (dd * gw));
        if (d == 0)
          p.DEC[(size_t)(b * 8 + h) * 1024 + t] = fminf(fmaxf(dd * gf, 1e-6f), 0.999f);
      }
    }
  }
  grid.sync();

  // P3: cumulative log-decay + update weights (16 (b,h), wave 0)
  if (bid < 16 && tid < 64) {
    int bh = bid, lane = tid;
    size_t base = (size_t)bh * 1024 + lane * 16;
    float loc[16];
    float run = 0.f;
#pragma unroll
    for (int i = 0; i < 16; ++i) { run += logf(p.DEC[base + i]); loc[i] = run; }
    float xx = run;
#pragma unroll
    for (int o = 1; o < 64; o <<= 1) {
      float v = __shfl_up(xx, o);
      if (lane >= o) xx += v;
    }
    float excl = xx - run;
#pragma unroll
    for (int i = 0; i < 16; ++i) {
      float L = excl + loc[i];
      p.LC[base + i] = L;
      float c = expf(L);
      p.WW[base + i] = c / (c + 1e-8f);
    }
  }
  grid.sync();

  // P4: local chunk scans (256 blocks = chunk,h,b)
  {
    int chunk = bid & 15, h = (bid >> 4) & 7, b = bid >> 7;
    int bh = b * 8 + h;
    int t0 = chunk * 64;
    float* sk = (float*)smem;
    float* sq = sk + 4096;
    float* sv = sq + 4096;
    float* lsa = sv + 4096;
    float* lsw = lsa + 64;
    int lane = tid & 63, wave = tid >> 6;
    const u16* gk = p.KB + ((size_t)bh * 1024 + t0) * 64;
    const u16* gq = p.QB + ((size_t)bh * 1024 + t0) * 64;
    const u16* gv = p.VG + ((size_t)bh * 1024 + t0) * 64;
#pragma unroll
    for (int r = 0; r < 4; ++r) {
      int f = ((wave * 4 + r) * 64 + lane) * 4;
      *(float4*)&sk[f] = b4_to_f4(*(const uint2*)(gk + f));
      *(float4*)&sq[f] = b4_to_f4(*(const uint2*)(gq + f));
      *(float4*)&sv[f] = b4_to_f4(*(const uint2*)(gv + f));
    }
    if (tid < 64) {
      lsa[tid] = p.DEC[(size_t)bh * 1024 + t0 + tid];
      lsw[tid] = p.WW[(size_t)bh * 1024 + t0 + tid];
    }
    __syncthreads();
    int i = tid >> 2, j0 = (tid & 3) * 16;
    float s[16];
#pragma unroll
    for (int z = 0; z < 16; ++z) s[z] = 0.f;
    for (int t = 0; t < 64; ++t) {
      float a = lsa[t], w = lsw[t];
      float wv = w * sv[t * 64 + i];
      float r = 0.f;
#pragma unroll
      for (int u4 = 0; u4 < 4; ++u4) {
        float4 kv = *(const float4*)&sk[t * 64 + j0 + u4 * 4];
        float4 qv = *(const float4*)&sq[t * 64 + j0 + u4 * 4];
        s[u4 * 4 + 0] = fmaf(a, s[u4 * 4 + 0], wv * kv.x); r = fmaf(s[u4 * 4 + 0], qv.x, r);
        s[u4 * 4 + 1] = fmaf(a, s[u4 * 4 + 1], wv * kv.y); r = fmaf(s[u4 * 4 + 1], qv.y, r);
        s[u4 * 4 + 2] = fmaf(a, s[u4 * 4 + 2], wv * kv.z); r = fmaf(s[u4 * 4 + 2], qv.z, r);
        s[u4 * 4 + 3] = fmaf(a, s[u4 * 4 + 3], wv * kv.w); r = fmaf(s[u4 * 4 + 3], qv.w, r);
      }
      r += __shfl_xor(r, 1);
      r += __shfl_xor(r, 2);
      if ((tid & 3) == 0)
        p.RP[((size_t)(b * 1024 + t0 + t) * 8 + h) * 64 + i] = r;
    }
    float* Sf = p.SF + ((size_t)bh * 16 + chunk) * 4096 + i * 64 + j0;
#pragma unroll
    for (int u4 = 0; u4 < 4; ++u4) {
      float4 v;
      v.x = s[u4 * 4 + 0]; v.y = s[u4 * 4 + 1]; v.z = s[u4 * 4 + 2]; v.w = s[u4 * 4 + 3];
      *(float4*)&Sf[u4 * 4] = v;
    }
  }
  grid.sync();

  // P5: cross-chunk combine, fully parallel (block = (bh, 256-elem slice))
  {
    int bh = bid >> 4;
    int e = (bid & 15) * 256 + tid;
    float s = 0.f;
    for (int c = 0; c < 16; ++c) {
      p.SI[((size_t)bh * 16 + c) * 4096 + e] = s;
      float Lend = p.LC[(size_t)bh * 1024 + c * 64 + 63];
      float Lpre = c ? p.LC[(size_t)bh * 1024 + c * 64 - 1] : 0.f;
      float P = expf(Lend - Lpre);
      s = fmaf(P, s, p.SF[((size_t)bh * 16 + c) * 4096 + e]);
    }
    p.out1[(size_t)bh * 4096 + e] = s;
  }
  grid.sync();

  // P6: inter-chunk readout correction + bf16 AB
  {
    int chunk = bid & 15, h = (bid >> 4) & 7, b = bid >> 7;
    int bh = b * 8 + h;
    int t0 = chunk * 64;
    float* sq = (float*)smem;
    float* sL = sq + 4096;
    int lane = tid & 63, wave = tid >> 6;
    const u16* gq = p.QB + ((size_t)bh * 1024 + t0) * 64;
#pragma unroll
    for (int r = 0; r < 4; ++r) {
      int f = ((wave * 4 + r) * 64 + lane) * 4;
      *(float4*)&sq[f] = b4_to_f4(*(const uint2*)(gq + f));
    }
    if (tid < 64) sL[tid] = p.LC[(size_t)bh * 1024 + t0 + tid];
    __syncthreads();
    float Lpre = chunk ? p.LC[(size_t)bh * 1024 + t0 - 1] : 0.f;
    int i = tid >> 2, j0 = (tid & 3) * 16;
    const float* Si = p.SI + ((size_t)bh * 16 + chunk) * 4096 + i * 64 + j0;
    float S[16];
#pragma unroll
    for (int u4 = 0; u4 < 4; ++u4) {
      float4 v = *(const float4*)&Si[u4 * 4];
      S[u4 * 4 + 0] = v.x; S[u4 * 4 + 1] = v.y; S[u4 * 4 + 2] = v.z; S[u4 * 4 + 3] = v.w;
    }
    for (int t = 0; t < 64; ++t) {
      float pp = expf(sL[t] - Lpre);
      float r = 0.f;
#pragma unroll
      for (int u4 = 0; u4 < 4; ++u4) {
        float4 qv = *(const float4*)&sq[t * 64 + j0 + u4 * 4];
        r = fmaf(S[u4 * 4 + 0], qv.x, r);
        r = fmaf(S[u4 * 4 + 1], qv.y, r);
        r = fmaf(S[u4 * 4 + 2], qv.z, r);
        r = fmaf(S[u4 * 4 + 3], qv.w, r);
      }
      r += __shfl_xor(r, 1);
      r += __shfl_xor(r, 2);
      if ((tid & 3) == 0) {
        size_t gi = ((size_t)(b * 1024 + t0 + t) * 8 + h) * 64 + i;
        p.AB[gi] = f2b(p.RP[gi] + pp * r);
      }
    }
  }
  grid.sync();

  // P7: Wo GEMM + x2 residual epilogue
  gemm_phase<64, 64, 1>(bid, tid, smem, p.AB, p.WTO, p.bo, p.X2, nullptr, nullptr,
                        p.x, p.motif, 2048, 512, 512);
  grid.sync();

  // P8: LN2 (8 rows/block)
  {
    float* red = (float*)smem;
    for (int r = 0; r < 8; ++r) {
      int row = bid * 8 + r;
      ln_row(p.X2 + (size_t)row * 512, p.ln2g, p.ln2b, p.HB + (size_t)row * 512, tid, red);
    }
  }
  grid.sync();

  // P9: FFN1 GEMM + gelu epilogue
  gemm_phase<128, 128, 2>(bid, tid, smem, p.HB, p.WT1, p.b1, nullptr, nullptr, p.MID,
                          nullptr, nullptr, 2048, 2048, 512);
  grid.sync();

  // P10: FFN2 GEMM + x3 epilogue
  gemm_phase<64, 64, 3>(bid, tid, smem, p.MID, p.WT2, p.b2, p.out0, nullptr, p.X3B,
                        p.X2, nullptr, 2048, 512, 2048);
  grid.sync();

  // P11: probe GEMM + out2/out3 epilogue
  gemm_phase<64, 64, 4>(bid, tid, smem, p.X3B, p.WTPS, p.bps, p.out2, p.out3, nullptr,
                        p.bmin, p.bmax, 2048, 512, 512);
}

// ---------------------------------------------------------------------------
extern "C" void kernel_launch(void* const* d_in, const int* in_sizes, int n_in,
                              void* d_out, int out_size, void* d_ws, size_t ws_size,
                              hipStream_t stream) {
  const float* x = (const float*)d_in[0];
  const float* bmin = (const float*)d_in[1];
  const float* bmax = (const float*)d_in[2];
  const float* motif = (const float*)d_in[3];
  const float* Wk = (const float*)d_in[4];
  const float* bk = (const float*)d_in[5];
  const float* Wq = (const float*)d_in[6];
  const float* bq = (const float*)d_in[7];
  const float* Wv = (const float*)d_in[8];
  const float* bv = (const float*)d_in[9];
  const float* Wo = (const float*)d_in[10];
  const float* bo = (const float*)d_in[11];
  const float* Wd = (const float*)d_in[12];
  const float* bd = (const float*)d_in[13];
  const float* Wgw = (const float*)d_in[14];
  const float* bgw = (const float*)d_in[15];
  const float* Wgf = (const float*)d_in[16];
  const float* bgf = (const float*)d_in[17];
  const float* Wps = (const float*)d_in[18];
  const float* bps = (const float*)d_in[19];
  const float* ln1g = (const float*)d_in[20];
  const float* ln1b = (const float*)d_in[21];
  const float* ln2g = (const float*)d_in[22];
  const float* ln2b = (const float*)d_in[23];
  const float* W1 = (const float*)d_in[24];
  const float* b1 = (const float*)d_in[25];
  const float* W2 = (const float*)d_in[26];
  const float* b2 = (const float*)d_in[27];

  char* ws = (char*)d_ws;
  u16* WTQ = (u16*)(ws + 0);
  u16* WTO = (u16*)(ws + 1703936);
  u16* WT1 = (u16*)(ws + 2228224);
  u16* WT2 = (u16*)(ws + 4325376);
  u16* WTPS = (u16*)(ws + 6422528);
  float* BQV = (float*)(ws + 6946816);
  u16* XN = (u16*)(ws + 6953984);
  float* C0 = (float*)(ws + 9051136);
  u16* KB = (u16*)(ws + 25828352);
  u16* QB = (u16*)(ws + 27925504);
  u16* VG = (u16*)(ws + 30022656);
  float* DEC = (float*)(ws + 32119808);
  float* LC = (float*)(ws + 32185344);
  float* WW = (float*)(ws + 32250880);
  float* RP = (float*)(ws + 32316416);
  float* SF = (float*)(ws + 36510720);
  float* SI = (float*)(ws + 40705024);
  u16* AB = (u16*)(ws + 9051136);      // aliases C0 (dead after P2)
  float* X2 = (float*)(ws + 11148288); // within old C0 region
  u16* HB = (u16*)(ws + 15342592);
  u16* MID = (u16*)(ws + 17439744);
  u16* X3B = (u16*)(ws + 25828352);    // aliases KB (dead after P6)

  float* out0 = (float*)d_out;
  float* out1 = out0 + 1048576;
  float* out2 = out0 + 1114112;
  float* out3 = out0 + 2162688;

  prep_weights<<<5440, 256, 0, stream>>>(Wk, Wq, Wv, Wo, Wps, W1, W2, Wd, Wgw, Wgf,
                                         bk, bq, bv, bd, bgw, bgf, x, ln1g, ln1b,
                                         WTQ, WTO, WTPS, WT1, WT2, BQV, XN);

  MP p;
  p.x = x; p.bmin = bmin; p.bmax = bmax; p.motif = motif;
  p.bo = bo; p.b1 = b1; p.b2 = b2; p.bps = bps; p.ln2g = ln2g; p.ln2b = ln2b;
  p.WTQ = WTQ; p.WTO = WTO; p.WT1 = WT1; p.WT2 = WT2; p.WTPS = WTPS; p.XN = XN;
  p.BQV = BQV; p.C0 = C0; p.KB = KB; p.QB = QB; p.VG = VG;
  p.DEC = DEC; p.LC = LC; p.WW = WW; p.RP = RP; p.SF = SF; p.SI = SI;
  p.AB = AB; p.HB = HB; p.MID = MID; p.X3B = X3B; p.X2 = X2;
  p.out0 = out0; p.out1 = out1; p.out2 = out2; p.out3 = out3;
  void* kargs[] = {(void*)&p};
  hipLaunchCooperativeKernel((void*)mega, dim3(256), dim3(256), kargs, 0, stream);
}

// Round 6
// 263.957 us; speedup vs baseline: 2.2420x; 2.2420x over previous
//
#include <hip/hip_runtime.h>

// HoloGraphBlockV7 — round 6: back to multi-kernel (round-4 skeleton; the
// cooperative mega-kernel pinned every phase at 1 block/CU and regressed 2x).
// Changes vs round 4: all GEMMs 64x64-tile + 3-stage pipeline (more blocks/CU,
// TLP covers the staging latency), scan cross-chunk combine parallelized
// (16 -> 256 blocks), LN1 folded into the prep kernel.

typedef unsigned short u16;
typedef unsigned int u32;
typedef __attribute__((ext_vector_type(8))) short short8;
typedef __attribute__((ext_vector_type(4))) float floatx4;

__device__ __forceinline__ float b2f(u16 u) {
  u32 x = ((u32)u) << 16;
  return __uint_as_float(x);
}
__device__ __forceinline__ u16 f2b(float f) {
  u32 x = __float_as_uint(f);
  u32 r = (x + 0x7fffu + ((x >> 16) & 1u)) >> 16;
  return (u16)r;
}
__device__ __forceinline__ float4 b4_to_f4(uint2 u) {
  float4 r;
  r.x = __uint_as_float((u.x & 0xffffu) << 16);
  r.y = __uint_as_float(u.x & 0xffff0000u);
  r.z = __uint_as_float((u.y & 0xffffu) << 16);
  r.w = __uint_as_float(u.y & 0xffff0000u);
  return r;
}

__device__ __forceinline__ void stage16(const u16* g, u16* lds_wave_base) {
  __builtin_amdgcn_global_load_lds((const __attribute__((address_space(1))) void*)g,
                                   (__attribute__((address_space(3))) void*)lds_wave_base,
                                   16, 0, 0);
}

// Stage a ROWSx32 bf16 tile (k-block kb) into LDS [row][32] with k-quad XOR
// swizzle: LDS(row, c) holds global k-quad c ^ ((row>>1)&3).
template <int ROWS>
__device__ __forceinline__ void stage_tile(const u16* __restrict__ G, int ldK, int kb,
                                           u16* lds, int tid) {
#pragma unroll
  for (int r = 0; r < ROWS / 64; ++r) {
    int slot = r * 256 + tid;
    int row = slot >> 2;
    int kwg = (slot & 3) ^ ((row >> 1) & 3);
    stage16(G + (size_t)row * ldK + kb * 32 + kwg * 8,
            lds + (size_t)(r * 256 + (tid >> 6) * 64) * 8);
  }
}

// ---------------------------------------------------------------------------
// LayerNorm of one 512-row; 256 threads.
__device__ __forceinline__ void ln_row(const float* __restrict__ xr,
                                       const float* __restrict__ g,
                                       const float* __restrict__ bt,
                                       u16* __restrict__ yr, int tid, float* red) {
  float x0 = xr[tid], x1 = xr[tid + 256];
  float s = x0 + x1, ss = x0 * x0 + x1 * x1;
#pragma unroll
  for (int o = 32; o > 0; o >>= 1) { s += __shfl_xor(s, o); ss += __shfl_xor(ss, o); }
  if ((tid & 63) == 0) { red[tid >> 6] = s; red[4 + (tid >> 6)] = ss; }
  __syncthreads();
  float ts = red[0] + red[1] + red[2] + red[3];
  float tss = red[4] + red[5] + red[6] + red[7];
  float mu = ts * (1.f / 512.f);
  float var = tss * (1.f / 512.f) - mu * mu;
  float rstd = 1.0f / sqrtf(var + 1e-5f);
  yr[tid] = f2b((x0 - mu) * rstd * g[tid] + bt[tid]);
  yr[tid + 256] = f2b((x1 - mu) * rstd * g[tid + 256] + bt[tid + 256]);
}

// ---------------------------------------------------------------------------
// Prep: weight transposes f32->bf16 (0..3327), gate/bias pack (3328..3391),
// LN1 rows (3392..5439).
__global__ __launch_bounds__(256) void prep_weights(
    const float* __restrict__ Wk, const float* __restrict__ Wq,
    const float* __restrict__ Wv, const float* __restrict__ Wo,
    const float* __restrict__ Wps, const float* __restrict__ W1,
    const float* __restrict__ W2, const float* __restrict__ Wd,
    const float* __restrict__ Wgw, const float* __restrict__ Wgf,
    const float* __restrict__ bk, const float* __restrict__ bq,
    const float* __restrict__ bv, const float* __restrict__ bd,
    const float* __restrict__ bgw, const float* __restrict__ bgf,
    const float* __restrict__ x, const float* __restrict__ ln1g,
    const float* __restrict__ ln1b,
    u16* __restrict__ WTQ, u16* __restrict__ WTO, u16* __restrict__ WTPS,
    u16* __restrict__ WT1, u16* __restrict__ WT2, float* __restrict__ BQV,
    u16* __restrict__ XN) {
  int bid = blockIdx.x, tid = threadIdx.x;
  __shared__ float tile[32][33];
  __shared__ float red[8];
  if (bid < 3328) {
    const float* src;
    u16* dst;
    int C, rel, tiles_x;
    if (bid < 256)       { src = Wk;  dst = WTQ;           C = 512;  rel = bid;        tiles_x = 16; }
    else if (bid < 512)  { src = Wq;  dst = WTQ + 262144;  C = 512;  rel = bid - 256;  tiles_x = 16; }
    else if (bid < 768)  { src = Wv;  dst = WTQ + 524288;  C = 512;  rel = bid - 512;  tiles_x = 16; }
    else if (bid < 1024) { src = Wo;  dst = WTO;           C = 512;  rel = bid - 768;  tiles_x = 16; }
    else if (bid < 1280) { src = Wps; dst = WTPS;          C = 512;  rel = bid - 1024; tiles_x = 16; }
    else if (bid < 2304) { src = W1;  dst = WT1;           C = 2048; rel = bid - 1280; tiles_x = 64; }
    else                 { src = W2;  dst = WT2;           C = 512;  rel = bid - 2304; tiles_x = 16; }
    int R = (bid >= 1280 && bid < 2304) ? 512 : (bid >= 2304 ? 2048 : 512);
    int c0 = (rel % tiles_x) * 32, r0 = (rel / tiles_x) * 32;
    int tx = tid & 31, ty = tid >> 5;
#pragma unroll
    for (int i = 0; i < 4; ++i)
      tile[ty + i * 8][tx] = src[(size_t)(r0 + ty + i * 8) * C + c0 + tx];
    __syncthreads();
#pragma unroll
    for (int i = 0; i < 4; ++i)
      dst[(size_t)(c0 + ty + i * 8) * R + r0 + tx] = f2b(tile[tx][ty + i * 8]);
  } else if (bid < 3392) {
    int idx = (bid - 3328) * 256 + tid;
    const int stride = 64 * 256;
    for (int i = idx; i < 128 * 512; i += stride) {
      int local = i >> 9, k = i & 511;
      float v = 0.f;
      if (local < 8) v = Wd[k * 8 + local];
      else if (local < 16) v = Wgw[k * 8 + (local - 8)];
      else if (local < 24) v = Wgf[k * 8 + (local - 16)];
      WTQ[(size_t)(1536 + local) * 512 + k] = f2b(v);
    }
    for (int i = idx; i < 1664; i += stride) {
      float v = 0.f;
      if (i < 512) v = bk[i];
      else if (i < 1024) v = bq[i - 512];
      else if (i < 1536) v = bv[i - 1024];
      else if (i < 1544) v = bd[i - 1536];
      else if (i < 1552) v = bgw[i - 1544];
      else if (i < 1560) v = bgf[i - 1552];
      BQV[i] = v;
    }
  } else {
    int row = bid - 3392;
    ln_row(x + (size_t)row * 512, ln1g, ln1b, XN + (size_t)row * 512, tid, red);
  }
}

// Standalone LN2.
__global__ __launch_bounds__(256) void ln_f32(const float* __restrict__ X,
                                              const float* __restrict__ g,
                                              const float* __restrict__ bt,
                                              u16* __restrict__ Y) {
  __shared__ float red[8];
  ln_row(X + (size_t)blockIdx.x * 512, g, bt, Y + (size_t)blockIdx.x * 512,
         threadIdx.x, red);
}

// ---------------------------------------------------------------------------
// 64x64-tile, 3-stage-pipelined bf16 MFMA GEMM with fused epilogues.
// 256 threads = 2x2 waves, each 32x32 (2x2 MFMA 16x16x32). 24 KB LDS.
// EPI 0: outf=v; 1: outf=aux0+v+0.1*aux1; 2: outb=bf16(gelu(v));
// 3: w=aux0+v, outf=w, outb=bf16(w); 4: outf=aux0+v, outf2=aux1+v.
template <int EPI>
__global__ __launch_bounds__(256, 4) void gemm64(
    const u16* __restrict__ A, const u16* __restrict__ BT, const float* __restrict__ bias,
    float* __restrict__ outf, float* __restrict__ outf2, u16* __restrict__ outb,
    const float* __restrict__ aux0, const float* __restrict__ aux1, int M, int N, int K) {
  __shared__ __align__(16) u16 As[3][64 * 32];
  __shared__ __align__(16) u16 Bs[3][64 * 32];
  const int tid = threadIdx.x;
  const int lane = tid & 63, wave = tid >> 6;
  const int wm = wave >> 1, wn = wave & 1;
  const int m0 = blockIdx.y * 64, n0 = blockIdx.x * 64;
  floatx4 acc[2][2] = {};
  const int fr = lane & 15, kq = lane >> 4;
  const int nk = K >> 5;
  const u16* Ab = A + (size_t)m0 * K;
  const u16* Bb = BT + (size_t)n0 * K;

  stage_tile<64>(Ab, K, 0, As[0], tid);
  stage_tile<64>(Bb, K, 0, Bs[0], tid);
  if (nk > 1) {
    stage_tile<64>(Ab, K, 1, As[1], tid);
    stage_tile<64>(Bb, K, 1, Bs[1], tid);
  }

  for (int kb = 0; kb < nk; ++kb) {
    const int cur = kb % 3;
    if (kb + 2 < nk) {
      const int nxt = (kb + 2) % 3;
      stage_tile<64>(Ab, K, kb + 2, As[nxt], tid);
      stage_tile<64>(Bb, K, kb + 2, Bs[nxt], tid);
    }
    int ahead = nk - 1 - kb;
    if (ahead > 2) ahead = 2;
    if (ahead == 2) asm volatile("s_waitcnt vmcnt(4)" ::: "memory");
    else if (ahead == 1) asm volatile("s_waitcnt vmcnt(2)" ::: "memory");
    else asm volatile("s_waitcnt vmcnt(0)" ::: "memory");
    asm volatile("s_barrier" ::: "memory");

    short8 af[2], bf[2];
#pragma unroll
    for (int mt = 0; mt < 2; ++mt) {
      int row = wm * 32 + mt * 16 + fr;
      af[mt] = *(const short8*)&As[cur][row * 32 + (kq ^ ((row >> 1) & 3)) * 8];
    }
#pragma unroll
    for (int nt = 0; nt < 2; ++nt) {
      int row = wn * 32 + nt * 16 + fr;
      bf[nt] = *(const short8*)&Bs[cur][row * 32 + (kq ^ ((row >> 1) & 3)) * 8];
    }
#pragma unroll
    for (int mt = 0; mt < 2; ++mt)
#pragma unroll
      for (int nt = 0; nt < 2; ++nt)
        acc[mt][nt] =
            __builtin_amdgcn_mfma_f32_16x16x32_bf16(af[mt], bf[nt], acc[mt][nt], 0, 0, 0);
    asm volatile("s_waitcnt lgkmcnt(0)" ::: "memory");
    asm volatile("s_barrier" ::: "memory");
  }

  const int col = lane & 15;
  const int rbase = (lane >> 4) * 4;
#pragma unroll
  for (int nt = 0; nt < 2; ++nt) {
    int gc = n0 + wn * 32 + nt * 16 + col;
    float bvv = bias[gc];
#pragma unroll
    for (int mt = 0; mt < 2; ++mt) {
      int gr = m0 + wm * 32 + mt * 16 + rbase;
#pragma unroll
      for (int r = 0; r < 4; ++r) {
        size_t idx = (size_t)(gr + r) * N + gc;
        float v = acc[mt][nt][r] + bvv;
        if constexpr (EPI == 0) {
          outf[idx] = v;
        } else if constexpr (EPI == 1) {
          outf[idx] = aux0[idx] + v + 0.1f * aux1[idx];
        } else if constexpr (EPI == 2) {
          outb[idx] = f2b(0.5f * v * (1.f + erff(v * 0.70710678118654752f)));
        } else if constexpr (EPI == 3) {
          float w = aux0[idx] + v;
          outf[idx] = w;
          outb[idx] = f2b(w);
        } else {
          outf[idx] = aux0[idx] + v;
          outf2[idx] = aux1[idx] + v;
        }
      }
    }
  }
}

// ---------------------------------------------------------------------------
// Per-token epilogue of the QKV+gates GEMM.
__global__ __launch_bounds__(512) void post_qkvg(const float* __restrict__ C0,
                                                 u16* __restrict__ KB, u16* __restrict__ QB,
                                                 u16* __restrict__ VG,
                                                 float* __restrict__ DEC) {
  int tok = blockIdx.x;
  int b = tok >> 10, t = tok & 1023;
  int tid = threadIdx.x;
  int h = tid >> 6, d = tid & 63;
  const float* row = C0 + (size_t)tok * 1664;

  float dl = row[1536 + h], gwl = row[1544 + h], gfl = row[1552 + h];
  float dd = dl > 20.f ? dl : log1pf(expf(dl));
  float sw = 1.f / (1.f + expf(-gwl));
  float gw = sw * sw;
  float sf = 1.f / (1.f + expf(-gfl));
  float gf = 1.f - sf * sf;

  size_t obase = ((size_t)(b * 8 + h) * 1024 + t) * 64 + d;

  float kx = row[h * 64 + d];
  float ssk = kx * kx;
#pragma unroll
  for (int o = 32; o > 0; o >>= 1) ssk += __shfl_xor(ssk, o);
  KB[obase] = f2b(kx / fmaxf(sqrtf(ssk), 1e-12f));

  float qx = row[512 + h * 64 + d];
  float ssq = qx * qx;
#pragma unroll
  for (int o = 32; o > 0; o >>= 1) ssq += __shfl_xor(ssq, o);
  QB[obase] = f2b(qx / fmaxf(sqrtf(ssq), 1e-12f));

  float vx = tanhf(row[1024 + h * 64 + d]);
  VG[obase] = f2b(vx * (dd * gw));

  if (d == 0)
    DEC[(size_t)(b * 8 + h) * 1024 + t] = fminf(fmaxf(dd * gf, 1e-6f), 0.999f);
}

// Cumulative log-decay per (b,h); w_t = c/(c+1e-8), c = exp(Lcum).
__global__ void logcum(const float* __restrict__ DEC, float* __restrict__ LC,
                       float* __restrict__ WW) {
  int bh = blockIdx.x;
  int lane = threadIdx.x;  // 64
  size_t base = (size_t)bh * 1024 + lane * 16;
  float loc[16];
  float run = 0.f;
#pragma unroll
  for (int i = 0; i < 16; ++i) { run += logf(DEC[base + i]); loc[i] = run; }
  float x = run;
#pragma unroll
  for (int o = 1; o < 64; o <<= 1) {
    float v = __shfl_up(x, o);
    if (lane >= o) x += v;
  }
  float excl = x - run;
#pragma unroll
  for (int i = 0; i < 16; ++i) {
    float L = excl + loc[i];
    LC[base + i] = L;
    float c = expf(L);
    WW[base + i] = c / (c + 1e-8f);
  }
}

// ---------------------------------------------------------------------------
// Scan phase 1: per (chunk,h,b) local scan of 64 steps with zero init.
__global__ __launch_bounds__(256, 2) void scan_phase1(
    const u16* __restrict__ KB, const u16* __restrict__ QB, const u16* __restrict__ VG,
    const float* __restrict__ DEC, const float* __restrict__ WW,
    float* __restrict__ RP, float* __restrict__ SF) {
  int chunk = blockIdx.x, h = blockIdx.y, b = blockIdx.z;
  int bh = b * 8 + h;
  int t0 = chunk * 64;
  __shared__ __align__(16) float sk[4096], sq[4096], sv[4096];
  __shared__ float lsa[64], lsw[64];
  int tid = threadIdx.x, lane = tid & 63, wave = tid >> 6;

  const u16* gk = KB + ((size_t)bh * 1024 + t0) * 64;
  const u16* gq = QB + ((size_t)bh * 1024 + t0) * 64;
  const u16* gv = VG + ((size_t)bh * 1024 + t0) * 64;
#pragma unroll
  for (int r = 0; r < 4; ++r) {
    int f = ((wave * 4 + r) * 64 + lane) * 4;
    *(float4*)&sk[f] = b4_to_f4(*(const uint2*)(gk + f));
    *(float4*)&sq[f] = b4_to_f4(*(const uint2*)(gq + f));
    *(float4*)&sv[f] = b4_to_f4(*(const uint2*)(gv + f));
  }
  if (tid < 64) {
    lsa[tid] = DEC[(size_t)bh * 1024 + t0 + tid];
    lsw[tid] = WW[(size_t)bh * 1024 + t0 + tid];
  }
  __syncthreads();

  int i = tid >> 2, j0 = (tid & 3) * 16;
  float s[16];
#pragma unroll
  for (int z = 0; z < 16; ++z) s[z] = 0.f;

  for (int t = 0; t < 64; ++t) {
    float a = lsa[t], w = lsw[t];
    float wv = w * sv[t * 64 + i];
    float r = 0.f;
#pragma unroll
    for (int u4 = 0; u4 < 4; ++u4) {
      float4 kv = *(const float4*)&sk[t * 64 + j0 + u4 * 4];
      float4 qv = *(const float4*)&sq[t * 64 + j0 + u4 * 4];
      s[u4 * 4 + 0] = fmaf(a, s[u4 * 4 + 0], wv * kv.x); r = fmaf(s[u4 * 4 + 0], qv.x, r);
      s[u4 * 4 + 1] = fmaf(a, s[u4 * 4 + 1], wv * kv.y); r = fmaf(s[u4 * 4 + 1], qv.y, r);
      s[u4 * 4 + 2] = fmaf(a, s[u4 * 4 + 2], wv * kv.z); r = fmaf(s[u4 * 4 + 2], qv.z, r);
      s[u4 * 4 + 3] = fmaf(a, s[u4 * 4 + 3], wv * kv.w); r = fmaf(s[u4 * 4 + 3], qv.w, r);
    }
    r += __shfl_xor(r, 1);
    r += __shfl_xor(r, 2);
    if ((tid & 3) == 0)
      RP[((size_t)(b * 1024 + t0 + t) * 8 + h) * 64 + i] = r;
  }

  float* Sf = SF + ((size_t)bh * 16 + chunk) * 4096 + i * 64 + j0;
#pragma unroll
  for (int u4 = 0; u4 < 4; ++u4) {
    float4 v;
    v.x = s[u4 * 4 + 0]; v.y = s[u4 * 4 + 1]; v.z = s[u4 * 4 + 2]; v.w = s[u4 * 4 + 3];
    *(float4*)&Sf[u4 * 4] = v;
  }
}

// Scan phase 2: cross-chunk combine, fully parallel. 256 blocks:
// block = (bh, 256-element state slice); per-element serial chunk loop.
__global__ __launch_bounds__(256) void scan_phase2p(const float* __restrict__ SF,
                                                    const float* __restrict__ LC,
                                                    float* __restrict__ SI,
                                                    float* __restrict__ next_mem) {
  int bh = blockIdx.x >> 4;
  int e = (blockIdx.x & 15) * 256 + threadIdx.x;
  float s = 0.f;
  for (int c = 0; c < 16; ++c) {
    SI[((size_t)bh * 16 + c) * 4096 + e] = s;
    float Lend = LC[(size_t)bh * 1024 + c * 64 + 63];
    float Lpre = c ? LC[(size_t)bh * 1024 + c * 64 - 1] : 0.f;
    float P = expf(Lend - Lpre);
    s = fmaf(P, s, SF[((size_t)bh * 16 + c) * 4096 + e]);
  }
  next_mem[(size_t)bh * 4096 + e] = s;
}

// Scan phase 3: add inter-chunk contribution p_t*(Sinit @ q_t); bf16 readout.
__global__ __launch_bounds__(256, 2) void scan_phase3(
    const u16* __restrict__ QB, const float* __restrict__ SI, const float* __restrict__ LC,
    const float* __restrict__ RP, u16* __restrict__ AB) {
  int chunk = blockIdx.x, h = blockIdx.y, b = blockIdx.z;
  int bh = b * 8 + h;
  int t0 = chunk * 64;
  __shared__ __align__(16) float sq[4096];
  __shared__ float sL[64];
  int tid = threadIdx.x, lane = tid & 63, wave = tid >> 6;

  const u16* gq = QB + ((size_t)bh * 1024 + t0) * 64;
#pragma unroll
  for (int r = 0; r < 4; ++r) {
    int f = ((wave * 4 + r) * 64 + lane) * 4;
    *(float4*)&sq[f] = b4_to_f4(*(const uint2*)(gq + f));
  }
  if (tid < 64) sL[tid] = LC[(size_t)bh * 1024 + t0 + tid];
  __syncthreads();

  float Lpre = chunk ? LC[(size_t)bh * 1024 + t0 - 1] : 0.f;
  int i = tid >> 2, j0 = (tid & 3) * 16;
  const float* Si = SI + ((size_t)bh * 16 + chunk) * 4096 + i * 64 + j0;
  float S[16];
#pragma unroll
  for (int u4 = 0; u4 < 4; ++u4) {
    float4 v = *(const float4*)&Si[u4 * 4];
    S[u4 * 4 + 0] = v.x; S[u4 * 4 + 1] = v.y; S[u4 * 4 + 2] = v.z; S[u4 * 4 + 3] = v.w;
  }

  for (int t = 0; t < 64; ++t) {
    float p = expf(sL[t] - Lpre);
    float r = 0.f;
#pragma unroll
    for (int u4 = 0; u4 < 4; ++u4) {
      float4 qv = *(const float4*)&sq[t * 64 + j0 + u4 * 4];
      r = fmaf(S[u4 * 4 + 0], qv.x, r);
      r = fmaf(S[u4 * 4 + 1], qv.y, r);
      r = fmaf(S[u4 * 4 + 2], qv.z, r);
      r = fmaf(S[u4 * 4 + 3], qv.w, r);
    }
    r += __shfl_xor(r, 1);
    r += __shfl_xor(r, 2);
    if ((tid & 3) == 0) {
      size_t gi = ((size_t)(b * 1024 + t0 + t) * 8 + h) * 64 + i;
      AB[gi] = f2b(RP[gi] + p * r);
    }
  }
}

// ---------------------------------------------------------------------------
extern "C" void kernel_launch(void* const* d_in, const int* in_sizes, int n_in,
                              void* d_out, int out_size, void* d_ws, size_t ws_size,
                              hipStream_t stream) {
  const float* x = (const float*)d_in[0];
  const float* bmin = (const float*)d_in[1];
  const float* bmax = (const float*)d_in[2];
  const float* motif = (const float*)d_in[3];
  const float* Wk = (const float*)d_in[4];
  const float* bk = (const float*)d_in[5];
  const float* Wq = (const float*)d_in[6];
  const float* bq = (const float*)d_in[7];
  const float* Wv = (const float*)d_in[8];
  const float* bv = (const float*)d_in[9];
  const float* Wo = (const float*)d_in[10];
  const float* bo = (const float*)d_in[11];
  const float* Wd = (const float*)d_in[12];
  const float* bd = (const float*)d_in[13];
  const float* Wgw = (const float*)d_in[14];
  const float* bgw = (const float*)d_in[15];
  const float* Wgf = (const float*)d_in[16];
  const float* bgf = (const float*)d_in[17];
  const float* Wps = (const float*)d_in[18];
  const float* bps = (const float*)d_in[19];
  const float* ln1g = (const float*)d_in[20];
  const float* ln1b = (const float*)d_in[21];
  const float* ln2g = (const float*)d_in[22];
  const float* ln2b = (const float*)d_in[23];
  const float* W1 = (const float*)d_in[24];
  const float* b1 = (const float*)d_in[25];
  const float* W2 = (const float*)d_in[26];
  const float* b2 = (const float*)d_in[27];

  char* ws = (char*)d_ws;
  u16* WTQ = (u16*)(ws + 0);
  u16* WTO = (u16*)(ws + 1703936);
  u16* WT1 = (u16*)(ws + 2228224);
  u16* WT2 = (u16*)(ws + 4325376);
  u16* WTPS = (u16*)(ws + 6422528);
  float* BQV = (float*)(ws + 6946816);
  u16* XN = (u16*)(ws + 6953984);
  float* C0 = (float*)(ws + 9051136);
  u16* KB = (u16*)(ws + 25828352);
  u16* QB = (u16*)(ws + 27925504);
  u16* VG = (u16*)(ws + 30022656);
  float* DEC = (float*)(ws + 32119808);
  float* LC = (float*)(ws + 32185344);
  float* WW = (float*)(ws + 32250880);
  float* RP = (float*)(ws + 32316416);
  float* SF = (float*)(ws + 36510720);
  float* SI = (float*)(ws + 40705024);
  u16* AB = (u16*)(ws + 9051136);      // aliases C0 (dead after post_qkvg)
  float* X2 = (float*)(ws + 11148288);
  u16* HB = (u16*)(ws + 15342592);
  u16* MID = (u16*)(ws + 17439744);
  u16* X3B = (u16*)(ws + 25828352);    // aliases KB (dead after scan3)

  float* out0 = (float*)d_out;
  float* out1 = out0 + 1048576;
  float* out2 = out0 + 1114112;
  float* out3 = out0 + 2162688;

  prep_weights<<<5440, 256, 0, stream>>>(Wk, Wq, Wv, Wo, Wps, W1, W2, Wd, Wgw, Wgf,
                                         bk, bq, bv, bd, bgw, bgf, x, ln1g, ln1b,
                                         WTQ, WTO, WTPS, WT1, WT2, BQV, XN);
  gemm64<0><<<dim3(26, 32), 256, 0, stream>>>(XN, WTQ, BQV, C0, nullptr, nullptr,
                                              nullptr, nullptr, 2048, 1664, 512);
  post_qkvg<<<2048, 512, 0, stream>>>(C0, KB, QB, VG, DEC);
  logcum<<<16, 64, 0, stream>>>(DEC, LC, WW);
  scan_phase1<<<dim3(16, 8, 2), 256, 0, stream>>>(KB, QB, VG, DEC, WW, RP, SF);
  scan_phase2p<<<256, 256, 0, stream>>>(SF, LC, SI, out1);
  scan_phase3<<<dim3(16, 8, 2), 256, 0, stream>>>(QB, SI, LC, RP, AB);

  gemm64<1><<<dim3(8, 32), 256, 0, stream>>>(AB, WTO, bo, X2, nullptr, nullptr,
                                             x, motif, 2048, 512, 512);
  ln_f32<<<2048, 256, 0, stream>>>(X2, ln2g, ln2b, HB);
  gemm64<2><<<dim3(32, 32), 256, 0, stream>>>(HB, WT1, b1, nullptr, nullptr, MID,
                                              nullptr, nullptr, 2048, 2048, 512);
  gemm64<3><<<dim3(8, 32), 256, 0, stream>>>(MID, WT2, b2, out0, nullptr, X3B,
                                             X2, nullptr, 2048, 512, 2048);
  gemm64<4><<<dim3(8, 32), 256, 0, stream>>>(X3B, WTPS, bps, out2, out3, nullptr,
                                             bmin, bmax, 2048, 512, 512);
}

// Round 7
// 258.747 us; speedup vs baseline: 2.2872x; 1.0201x over previous
//
#include <hip/hip_runtime.h>

// HoloGraphBlockV7 — round 7: BK=64 K-loop (half the barriers, 2x MFMA per
// barrier) + 32x64 tiles for the N=512 GEMMs (512 blocks = 2/CU instead of 1).
// LDS swizzle upgraded to chunk^=(row&7) for the 128B row stride.

typedef unsigned short u16;
typedef unsigned int u32;
typedef __attribute__((ext_vector_type(8))) short short8;
typedef __attribute__((ext_vector_type(4))) float floatx4;

__device__ __forceinline__ float b2f(u16 u) {
  u32 x = ((u32)u) << 16;
  return __uint_as_float(x);
}
__device__ __forceinline__ u16 f2b(float f) {
  u32 x = __float_as_uint(f);
  u32 r = (x + 0x7fffu + ((x >> 16) & 1u)) >> 16;
  return (u16)r;
}
__device__ __forceinline__ float4 b4_to_f4(uint2 u) {
  float4 r;
  r.x = __uint_as_float((u.x & 0xffffu) << 16);
  r.y = __uint_as_float(u.x & 0xffff0000u);
  r.z = __uint_as_float((u.y & 0xffffu) << 16);
  r.w = __uint_as_float(u.y & 0xffff0000u);
  return r;
}

__device__ __forceinline__ void stage16(const u16* g, u16* lds_wave_base) {
  __builtin_amdgcn_global_load_lds((const __attribute__((address_space(1))) void*)g,
                                   (__attribute__((address_space(3))) void*)lds_wave_base,
                                   16, 0, 0);
}

// Stage a ROWSx64 bf16 tile (64-wide k-block kb) into LDS [row][64] with
// chunk swizzle: LDS chunk slot m of row r holds global k-chunk m ^ (r&7).
template <int ROWS>
__device__ __forceinline__ void stage_tile64(const u16* __restrict__ G, int ldK, int kb,
                                             u16* lds, int tid) {
#pragma unroll
  for (int r = 0; r < ROWS / 32; ++r) {
    int slot = r * 256 + tid;
    int row = slot >> 3;
    int kwg = (slot & 7) ^ (row & 7);
    stage16(G + (size_t)row * ldK + kb * 64 + kwg * 8,
            lds + (size_t)(r * 256 + (tid >> 6) * 64) * 8);
  }
}

// ---------------------------------------------------------------------------
// LayerNorm of one 512-row; 256 threads.
__device__ __forceinline__ void ln_row(const float* __restrict__ xr,
                                       const float* __restrict__ g,
                                       const float* __restrict__ bt,
                                       u16* __restrict__ yr, int tid, float* red) {
  float x0 = xr[tid], x1 = xr[tid + 256];
  float s = x0 + x1, ss = x0 * x0 + x1 * x1;
#pragma unroll
  for (int o = 32; o > 0; o >>= 1) { s += __shfl_xor(s, o); ss += __shfl_xor(ss, o); }
  if ((tid & 63) == 0) { red[tid >> 6] = s; red[4 + (tid >> 6)] = ss; }
  __syncthreads();
  float ts = red[0] + red[1] + red[2] + red[3];
  float tss = red[4] + red[5] + red[6] + red[7];
  float mu = ts * (1.f / 512.f);
  float var = tss * (1.f / 512.f) - mu * mu;
  float rstd = 1.0f / sqrtf(var + 1e-5f);
  yr[tid] = f2b((x0 - mu) * rstd * g[tid] + bt[tid]);
  yr[tid + 256] = f2b((x1 - mu) * rstd * g[tid + 256] + bt[tid + 256]);
}

// ---------------------------------------------------------------------------
// Prep: weight transposes f32->bf16 (0..3327), gate/bias pack (3328..3391),
// LN1 rows (3392..5439).
__global__ __launch_bounds__(256) void prep_weights(
    const float* __restrict__ Wk, const float* __restrict__ Wq,
    const float* __restrict__ Wv, const float* __restrict__ Wo,
    const float* __restrict__ Wps, const float* __restrict__ W1,
    const float* __restrict__ W2, const float* __restrict__ Wd,
    const float* __restrict__ Wgw, const float* __restrict__ Wgf,
    const float* __restrict__ bk, const float* __restrict__ bq,
    const float* __restrict__ bv, const float* __restrict__ bd,
    const float* __restrict__ bgw, const float* __restrict__ bgf,
    const float* __restrict__ x, const float* __restrict__ ln1g,
    const float* __restrict__ ln1b,
    u16* __restrict__ WTQ, u16* __restrict__ WTO, u16* __restrict__ WTPS,
    u16* __restrict__ WT1, u16* __restrict__ WT2, float* __restrict__ BQV,
    u16* __restrict__ XN) {
  int bid = blockIdx.x, tid = threadIdx.x;
  __shared__ float tile[32][33];
  __shared__ float red[8];
  if (bid < 3328) {
    const float* src;
    u16* dst;
    int C, rel, tiles_x;
    if (bid < 256)       { src = Wk;  dst = WTQ;           C = 512;  rel = bid;        tiles_x = 16; }
    else if (bid < 512)  { src = Wq;  dst = WTQ + 262144;  C = 512;  rel = bid - 256;  tiles_x = 16; }
    else if (bid < 768)  { src = Wv;  dst = WTQ + 524288;  C = 512;  rel = bid - 512;  tiles_x = 16; }
    else if (bid < 1024) { src = Wo;  dst = WTO;           C = 512;  rel = bid - 768;  tiles_x = 16; }
    else if (bid < 1280) { src = Wps; dst = WTPS;          C = 512;  rel = bid - 1024; tiles_x = 16; }
    else if (bid < 2304) { src = W1;  dst = WT1;           C = 2048; rel = bid - 1280; tiles_x = 64; }
    else                 { src = W2;  dst = WT2;           C = 512;  rel = bid - 2304; tiles_x = 16; }
    int R = (bid >= 1280 && bid < 2304) ? 512 : (bid >= 2304 ? 2048 : 512);
    int c0 = (rel % tiles_x) * 32, r0 = (rel / tiles_x) * 32;
    int tx = tid & 31, ty = tid >> 5;
#pragma unroll
    for (int i = 0; i < 4; ++i)
      tile[ty + i * 8][tx] = src[(size_t)(r0 + ty + i * 8) * C + c0 + tx];
    __syncthreads();
#pragma unroll
    for (int i = 0; i < 4; ++i)
      dst[(size_t)(c0 + ty + i * 8) * R + r0 + tx] = f2b(tile[tx][ty + i * 8]);
  } else if (bid < 3392) {
    int idx = (bid - 3328) * 256 + tid;
    const int stride = 64 * 256;
    for (int i = idx; i < 128 * 512; i += stride) {
      int local = i >> 9, k = i & 511;
      float v = 0.f;
      if (local < 8) v = Wd[k * 8 + local];
      else if (local < 16) v = Wgw[k * 8 + (local - 8)];
      else if (local < 24) v = Wgf[k * 8 + (local - 16)];
      WTQ[(size_t)(1536 + local) * 512 + k] = f2b(v);
    }
    for (int i = idx; i < 1664; i += stride) {
      float v = 0.f;
      if (i < 512) v = bk[i];
      else if (i < 1024) v = bq[i - 512];
      else if (i < 1536) v = bv[i - 1024];
      else if (i < 1544) v = bd[i - 1536];
      else if (i < 1552) v = bgw[i - 1544];
      else if (i < 1560) v = bgf[i - 1552];
      BQV[i] = v;
    }
  } else {
    int row = bid - 3392;
    ln_row(x + (size_t)row * 512, ln1g, ln1b, XN + (size_t)row * 512, tid, red);
  }
}

// Standalone LN2.
__global__ __launch_bounds__(256) void ln_f32(const float* __restrict__ X,
                                              const float* __restrict__ g,
                                              const float* __restrict__ bt,
                                              u16* __restrict__ Y) {
  __shared__ float red[8];
  ln_row(X + (size_t)blockIdx.x * 512, g, bt, Y + (size_t)blockIdx.x * 512,
         threadIdx.x, red);
}

// ---------------------------------------------------------------------------
// BMx64-tile, BK=64, 3-stage-pipelined bf16 MFMA GEMM with fused epilogues.
// 256 threads = 2x2 waves, each (BM/2)x32. BM in {64,32}.
// EPI 0: outf=v; 1: outf=aux0+v+0.1*aux1; 2: outb=bf16(gelu(v));
// 3: w=aux0+v, outf=w, outb=bf16(w); 4: outf=aux0+v, outf2=aux1+v.
template <int BM, int EPI>
__global__ __launch_bounds__(256, (BM == 64 ? 3 : 4)) void gemm64k(
    const u16* __restrict__ A, const u16* __restrict__ BT, const float* __restrict__ bias,
    float* __restrict__ outf, float* __restrict__ outf2, u16* __restrict__ outb,
    const float* __restrict__ aux0, const float* __restrict__ aux1, int M, int N, int K) {
  constexpr int MT = BM / 32;          // 16-row mfma tiles per wave
  constexpr int S = BM / 32 + 2;       // DMA insts per thread per k-tile
  __shared__ __align__(16) u16 As[3][BM * 64];
  __shared__ __align__(16) u16 Bs[3][64 * 64];
  const int tid = threadIdx.x;
  const int lane = tid & 63, wave = tid >> 6;
  const int wm = wave >> 1, wn = wave & 1;
  const int m0 = blockIdx.y * BM, n0 = blockIdx.x * 64;
  floatx4 acc[MT][2] = {};
  const int fr = lane & 15, kq = lane >> 4;
  const int nk = K >> 6;
  const u16* Ab = A + (size_t)m0 * K;
  const u16* Bb = BT + (size_t)n0 * K;

  stage_tile64<BM>(Ab, K, 0, As[0], tid);
  stage_tile64<64>(Bb, K, 0, Bs[0], tid);
  if (nk > 1) {
    stage_tile64<BM>(Ab, K, 1, As[1], tid);
    stage_tile64<64>(Bb, K, 1, Bs[1], tid);
  }

  for (int kb = 0; kb < nk; ++kb) {
    const int cur = kb % 3;
    if (kb + 2 < nk) {
      const int nxt = (kb + 2) % 3;
      stage_tile64<BM>(Ab, K, kb + 2, As[nxt], tid);
      stage_tile64<64>(Bb, K, kb + 2, Bs[nxt], tid);
    }
    int ahead = nk - 1 - kb;
    if (ahead > 2) ahead = 2;
    if (ahead == 2) {
      if constexpr (S == 4) asm volatile("s_waitcnt vmcnt(8)" ::: "memory");
      else asm volatile("s_waitcnt vmcnt(6)" ::: "memory");
    } else if (ahead == 1) {
      if constexpr (S == 4) asm volatile("s_waitcnt vmcnt(4)" ::: "memory");
      else asm volatile("s_waitcnt vmcnt(3)" ::: "memory");
    } else {
      asm volatile("s_waitcnt vmcnt(0)" ::: "memory");
    }
    asm volatile("s_barrier" ::: "memory");

#pragma unroll
    for (int sub = 0; sub < 2; ++sub) {
      short8 af[MT], bf[2];
#pragma unroll
      for (int mt = 0; mt < MT; ++mt) {
        int row = wm * (BM / 2) + mt * 16 + fr;
        int c = sub * 4 + kq;
        af[mt] = *(const short8*)&As[cur][row * 64 + ((c ^ (row & 7)) << 3)];
      }
#pragma unroll
      for (int nt = 0; nt < 2; ++nt) {
        int row = wn * 32 + nt * 16 + fr;
        int c = sub * 4 + kq;
        bf[nt] = *(const short8*)&Bs[cur][row * 64 + ((c ^ (row & 7)) << 3)];
      }
#pragma unroll
      for (int mt = 0; mt < MT; ++mt)
#pragma unroll
        for (int nt = 0; nt < 2; ++nt)
          acc[mt][nt] =
              __builtin_amdgcn_mfma_f32_16x16x32_bf16(af[mt], bf[nt], acc[mt][nt], 0, 0, 0);
    }
    asm volatile("s_waitcnt lgkmcnt(0)" ::: "memory");
    asm volatile("s_barrier" ::: "memory");
  }

  const int col = lane & 15;
  const int rbase = (lane >> 4) * 4;
#pragma unroll
  for (int nt = 0; nt < 2; ++nt) {
    int gc = n0 + wn * 32 + nt * 16 + col;
    float bvv = bias[gc];
#pragma unroll
    for (int mt = 0; mt < MT; ++mt) {
      int gr = m0 + wm * (BM / 2) + mt * 16 + rbase;
#pragma unroll
      for (int r = 0; r < 4; ++r) {
        size_t idx = (size_t)(gr + r) * N + gc;
        float v = acc[mt][nt][r] + bvv;
        if constexpr (EPI == 0) {
          outf[idx] = v;
        } else if constexpr (EPI == 1) {
          outf[idx] = aux0[idx] + v + 0.1f * aux1[idx];
        } else if constexpr (EPI == 2) {
          outb[idx] = f2b(0.5f * v * (1.f + erff(v * 0.70710678118654752f)));
        } else if constexpr (EPI == 3) {
          float w = aux0[idx] + v;
          outf[idx] = w;
          outb[idx] = f2b(w);
        } else {
          outf[idx] = aux0[idx] + v;
          outf2[idx] = aux1[idx] + v;
        }
      }
    }
  }
}

// ---------------------------------------------------------------------------
// Per-token epilogue of the QKV+gates GEMM.
__global__ __launch_bounds__(512) void post_qkvg(const float* __restrict__ C0,
                                                 u16* __restrict__ KB, u16* __restrict__ QB,
                                                 u16* __restrict__ VG,
                                                 float* __restrict__ DEC) {
  int tok = blockIdx.x;
  int b = tok >> 10, t = tok & 1023;
  int tid = threadIdx.x;
  int h = tid >> 6, d = tid & 63;
  const float* row = C0 + (size_t)tok * 1664;

  float dl = row[1536 + h], gwl = row[1544 + h], gfl = row[1552 + h];
  float dd = dl > 20.f ? dl : log1pf(expf(dl));
  float sw = 1.f / (1.f + expf(-gwl));
  float gw = sw * sw;
  float sf = 1.f / (1.f + expf(-gfl));
  float gf = 1.f - sf * sf;

  size_t obase = ((size_t)(b * 8 + h) * 1024 + t) * 64 + d;

  float kx = row[h * 64 + d];
  float ssk = kx * kx;
#pragma unroll
  for (int o = 32; o > 0; o >>= 1) ssk += __shfl_xor(ssk, o);
  KB[obase] = f2b(kx / fmaxf(sqrtf(ssk), 1e-12f));

  float qx = row[512 + h * 64 + d];
  float ssq = qx * qx;
#pragma unroll
  for (int o = 32; o > 0; o >>= 1) ssq += __shfl_xor(ssq, o);
  QB[obase] = f2b(qx / fmaxf(sqrtf(ssq), 1e-12f));

  float vx = tanhf(row[1024 + h * 64 + d]);
  VG[obase] = f2b(vx * (dd * gw));

  if (d == 0)
    DEC[(size_t)(b * 8 + h) * 1024 + t] = fminf(fmaxf(dd * gf, 1e-6f), 0.999f);
}

// Cumulative log-decay per (b,h); w_t = c/(c+1e-8), c = exp(Lcum).
__global__ void logcum(const float* __restrict__ DEC, float* __restrict__ LC,
                       float* __restrict__ WW) {
  int bh = blockIdx.x;
  int lane = threadIdx.x;  // 64
  size_t base = (size_t)bh * 1024 + lane * 16;
  float loc[16];
  float run = 0.f;
#pragma unroll
  for (int i = 0; i < 16; ++i) { run += logf(DEC[base + i]); loc[i] = run; }
  float x = run;
#pragma unroll
  for (int o = 1; o < 64; o <<= 1) {
    float v = __shfl_up(x, o);
    if (lane >= o) x += v;
  }
  float excl = x - run;
#pragma unroll
  for (int i = 0; i < 16; ++i) {
    float L = excl + loc[i];
    LC[base + i] = L;
    float c = expf(L);
    WW[base + i] = c / (c + 1e-8f);
  }
}

// ---------------------------------------------------------------------------
// Scan phase 1: per (chunk,h,b) local scan of 64 steps with zero init.
__global__ __launch_bounds__(256, 2) void scan_phase1(
    const u16* __restrict__ KB, const u16* __restrict__ QB, const u16* __restrict__ VG,
    const float* __restrict__ DEC, const float* __restrict__ WW,
    float* __restrict__ RP, float* __restrict__ SF) {
  int chunk = blockIdx.x, h = blockIdx.y, b = blockIdx.z;
  int bh = b * 8 + h;
  int t0 = chunk * 64;
  __shared__ __align__(16) float sk[4096], sq[4096], sv[4096];
  __shared__ float lsa[64], lsw[64];
  int tid = threadIdx.x, lane = tid & 63, wave = tid >> 6;

  const u16* gk = KB + ((size_t)bh * 1024 + t0) * 64;
  const u16* gq = QB + ((size_t)bh * 1024 + t0) * 64;
  const u16* gv = VG + ((size_t)bh * 1024 + t0) * 64;
#pragma unroll
  for (int r = 0; r < 4; ++r) {
    int f = ((wave * 4 + r) * 64 + lane) * 4;
    *(float4*)&sk[f] = b4_to_f4(*(const uint2*)(gk + f));
    *(float4*)&sq[f] = b4_to_f4(*(const uint2*)(gq + f));
    *(float4*)&sv[f] = b4_to_f4(*(const uint2*)(gv + f));
  }
  if (tid < 64) {
    lsa[tid] = DEC[(size_t)bh * 1024 + t0 + tid];
    lsw[tid] = WW[(size_t)bh * 1024 + t0 + tid];
  }
  __syncthreads();

  int i = tid >> 2, j0 = (tid & 3) * 16;
  float s[16];
#pragma unroll
  for (int z = 0; z < 16; ++z) s[z] = 0.f;

  for (int t = 0; t < 64; ++t) {
    float a = lsa[t], w = lsw[t];
    float wv = w * sv[t * 64 + i];
    float r = 0.f;
#pragma unroll
    for (int u4 = 0; u4 < 4; ++u4) {
      float4 kv = *(const float4*)&sk[t * 64 + j0 + u4 * 4];
      float4 qv = *(const float4*)&sq[t * 64 + j0 + u4 * 4];
      s[u4 * 4 + 0] = fmaf(a, s[u4 * 4 + 0], wv * kv.x); r = fmaf(s[u4 * 4 + 0], qv.x, r);
      s[u4 * 4 + 1] = fmaf(a, s[u4 * 4 + 1], wv * kv.y); r = fmaf(s[u4 * 4 + 1], qv.y, r);
      s[u4 * 4 + 2] = fmaf(a, s[u4 * 4 + 2], wv * kv.z); r = fmaf(s[u4 * 4 + 2], qv.z, r);
      s[u4 * 4 + 3] = fmaf(a, s[u4 * 4 + 3], wv * kv.w); r = fmaf(s[u4 * 4 + 3], qv.w, r);
    }
    r += __shfl_xor(r, 1);
    r += __shfl_xor(r, 2);
    if ((tid & 3) == 0)
      RP[((size_t)(b * 1024 + t0 + t) * 8 + h) * 64 + i] = r;
  }

  float* Sf = SF + ((size_t)bh * 16 + chunk) * 4096 + i * 64 + j0;
#pragma unroll
  for (int u4 = 0; u4 < 4; ++u4) {
    float4 v;
    v.x = s[u4 * 4 + 0]; v.y = s[u4 * 4 + 1]; v.z = s[u4 * 4 + 2]; v.w = s[u4 * 4 + 3];
    *(float4*)&Sf[u4 * 4] = v;
  }
}

// Scan phase 2: cross-chunk combine, fully parallel (256 blocks).
__global__ __launch_bounds__(256) void scan_phase2p(const float* __restrict__ SF,
                                                    const float* __restrict__ LC,
                                                    float* __restrict__ SI,
                                                    float* __restrict__ next_mem) {
  int bh = blockIdx.x >> 4;
  int e = (blockIdx.x & 15) * 256 + threadIdx.x;
  float s = 0.f;
  for (int c = 0; c < 16; ++c) {
    SI[((size_t)bh * 16 + c) * 4096 + e] = s;
    float Lend = LC[(size_t)bh * 1024 + c * 64 + 63];
    float Lpre = c ? LC[(size_t)bh * 1024 + c * 64 - 1] : 0.f;
    float P = expf(Lend - Lpre);
    s = fmaf(P, s, SF[((size_t)bh * 16 + c) * 4096 + e]);
  }
  next_mem[(size_t)bh * 4096 + e] = s;
}

// Scan phase 3: add inter-chunk contribution p_t*(Sinit @ q_t); bf16 readout.
__global__ __launch_bounds__(256, 2) void scan_phase3(
    const u16* __restrict__ QB, const float* __restrict__ SI, const float* __restrict__ LC,
    const float* __restrict__ RP, u16* __restrict__ AB) {
  int chunk = blockIdx.x, h = blockIdx.y, b = blockIdx.z;
  int bh = b * 8 + h;
  int t0 = chunk * 64;
  __shared__ __align__(16) float sq[4096];
  __shared__ float sL[64];
  int tid = threadIdx.x, lane = tid & 63, wave = tid >> 6;

  const u16* gq = QB + ((size_t)bh * 1024 + t0) * 64;
#pragma unroll
  for (int r = 0; r < 4; ++r) {
    int f = ((wave * 4 + r) * 64 + lane) * 4;
    *(float4*)&sq[f] = b4_to_f4(*(const uint2*)(gq + f));
  }
  if (tid < 64) sL[tid] = LC[(size_t)bh * 1024 + t0 + tid];
  __syncthreads();

  float Lpre = chunk ? LC[(size_t)bh * 1024 + t0 - 1] : 0.f;
  int i = tid >> 2, j0 = (tid & 3) * 16;
  const float* Si = SI + ((size_t)bh * 16 + chunk) * 4096 + i * 64 + j0;
  float S[16];
#pragma unroll
  for (int u4 = 0; u4 < 4; ++u4) {
    float4 v = *(const float4*)&Si[u4 * 4];
    S[u4 * 4 + 0] = v.x; S[u4 * 4 + 1] = v.y; S[u4 * 4 + 2] = v.z; S[u4 * 4 + 3] = v.w;
  }

  for (int t = 0; t < 64; ++t) {
    float p = expf(sL[t] - Lpre);
    float r = 0.f;
#pragma unroll
    for (int u4 = 0; u4 < 4; ++u4) {
      float4 qv = *(const float4*)&sq[t * 64 + j0 + u4 * 4];
      r = fmaf(S[u4 * 4 + 0], qv.x, r);
      r = fmaf(S[u4 * 4 + 1], qv.y, r);
      r = fmaf(S[u4 * 4 + 2], qv.z, r);
      r = fmaf(S[u4 * 4 + 3], qv.w, r);
    }
    r += __shfl_xor(r, 1);
    r += __shfl_xor(r, 2);
    if ((tid & 3) == 0) {
      size_t gi = ((size_t)(b * 1024 + t0 + t) * 8 + h) * 64 + i;
      AB[gi] = f2b(RP[gi] + p * r);
    }
  }
}

// ---------------------------------------------------------------------------
extern "C" void kernel_launch(void* const* d_in, const int* in_sizes, int n_in,
                              void* d_out, int out_size, void* d_ws, size_t ws_size,
                              hipStream_t stream) {
  const float* x = (const float*)d_in[0];
  const float* bmin = (const float*)d_in[1];
  const float* bmax = (const float*)d_in[2];
  const float* motif = (const float*)d_in[3];
  const float* Wk = (const float*)d_in[4];
  const float* bk = (const float*)d_in[5];
  const float* Wq = (const float*)d_in[6];
  const float* bq = (const float*)d_in[7];
  const float* Wv = (const float*)d_in[8];
  const float* bv = (const float*)d_in[9];
  const float* Wo = (const float*)d_in[10];
  const float* bo = (const float*)d_in[11];
  const float* Wd = (const float*)d_in[12];
  const float* bd = (const float*)d_in[13];
  const float* Wgw = (const float*)d_in[14];
  const float* bgw = (const float*)d_in[15];
  const float* Wgf = (const float*)d_in[16];
  const float* bgf = (const float*)d_in[17];
  const float* Wps = (const float*)d_in[18];
  const float* bps = (const float*)d_in[19];
  const float* ln1g = (const float*)d_in[20];
  const float* ln1b = (const float*)d_in[21];
  const float* ln2g = (const float*)d_in[22];
  const float* ln2b = (const float*)d_in[23];
  const float* W1 = (const float*)d_in[24];
  const float* b1 = (const float*)d_in[25];
  const float* W2 = (const float*)d_in[26];
  const float* b2 = (const float*)d_in[27];

  char* ws = (char*)d_ws;
  u16* WTQ = (u16*)(ws + 0);
  u16* WTO = (u16*)(ws + 1703936);
  u16* WT1 = (u16*)(ws + 2228224);
  u16* WT2 = (u16*)(ws + 4325376);
  u16* WTPS = (u16*)(ws + 6422528);
  float* BQV = (float*)(ws + 6946816);
  u16* XN = (u16*)(ws + 6953984);
  float* C0 = (float*)(ws + 9051136);
  u16* KB = (u16*)(ws + 25828352);
  u16* QB = (u16*)(ws + 27925504);
  u16* VG = (u16*)(ws + 30022656);
  float* DEC = (float*)(ws + 32119808);
  float* LC = (float*)(ws + 32185344);
  float* WW = (float*)(ws + 32250880);
  float* RP = (float*)(ws + 32316416);
  float* SF = (float*)(ws + 36510720);
  float* SI = (float*)(ws + 40705024);
  u16* AB = (u16*)(ws + 9051136);      // aliases C0 (dead after post_qkvg)
  float* X2 = (float*)(ws + 11148288);
  u16* HB = (u16*)(ws + 15342592);
  u16* MID = (u16*)(ws + 17439744);
  u16* X3B = (u16*)(ws + 25828352);    // aliases KB (dead after scan3)

  float* out0 = (float*)d_out;
  float* out1 = out0 + 1048576;
  float* out2 = out0 + 1114112;
  float* out3 = out0 + 2162688;

  prep_weights<<<5440, 256, 0, stream>>>(Wk, Wq, Wv, Wo, Wps, W1, W2, Wd, Wgw, Wgf,
                                         bk, bq, bv, bd, bgw, bgf, x, ln1g, ln1b,
                                         WTQ, WTO, WTPS, WT1, WT2, BQV, XN);
  gemm64k<64, 0><<<dim3(26, 32), 256, 0, stream>>>(XN, WTQ, BQV, C0, nullptr, nullptr,
                                                   nullptr, nullptr, 2048, 1664, 512);
  post_qkvg<<<2048, 512, 0, stream>>>(C0, KB, QB, VG, DEC);
  logcum<<<16, 64, 0, stream>>>(DEC, LC, WW);
  scan_phase1<<<dim3(16, 8, 2), 256, 0, stream>>>(KB, QB, VG, DEC, WW, RP, SF);
  scan_phase2p<<<256, 256, 0, stream>>>(SF, LC, SI, out1);
  scan_phase3<<<dim3(16, 8, 2), 256, 0, stream>>>(QB, SI, LC, RP, AB);

  gemm64k<32, 1><<<dim3(8, 64), 256, 0, stream>>>(AB, WTO, bo, X2, nullptr, nullptr,
                                                  x, motif, 2048, 512, 512);
  ln_f32<<<2048, 256, 0, stream>>>(X2, ln2g, ln2b, HB);
  gemm64k<64, 2><<<dim3(32, 32), 256, 0, stream>>>(HB, WT1, b1, nullptr, nullptr, MID,
                                                   nullptr, nullptr, 2048, 2048, 512);
  gemm64k<32, 3><<<dim3(8, 64), 256, 0, stream>>>(MID, WT2, b2, out0, nullptr, X3B,
                                                  X2, nullptr, 2048, 512, 2048);
  gemm64k<32, 4><<<dim3(8, 64), 256, 0, stream>>>(X3B, WTPS, bps, out2, out3, nullptr,
                                                  bmin, bmax, 2048, 512, 512);
}

// Round 8
// 234.668 us; speedup vs baseline: 2.5218x; 1.1026x over previous
//
#include <hip/hip_runtime.h>

// HoloGraphBlockV7 — round 8: occupancy/residency-first.
// GEMMs: 2-stage LDS (32KB/24KB) so QKV(832 blocks) and FFN1(1024) are fully
// resident at 4 blocks/CU (no tail rounds); N=512 GEMMs at 6 blocks/CU.
// Scan: 32-token chunks -> 512 blocks = 2 blocks/CU on the LDS-bound phases.

typedef unsigned short u16;
typedef unsigned int u32;
typedef __attribute__((ext_vector_type(8))) short short8;
typedef __attribute__((ext_vector_type(4))) float floatx4;

__device__ __forceinline__ float b2f(u16 u) {
  u32 x = ((u32)u) << 16;
  return __uint_as_float(x);
}
__device__ __forceinline__ u16 f2b(float f) {
  u32 x = __float_as_uint(f);
  u32 r = (x + 0x7fffu + ((x >> 16) & 1u)) >> 16;
  return (u16)r;
}
__device__ __forceinline__ float4 b4_to_f4(uint2 u) {
  float4 r;
  r.x = __uint_as_float((u.x & 0xffffu) << 16);
  r.y = __uint_as_float(u.x & 0xffff0000u);
  r.z = __uint_as_float((u.y & 0xffffu) << 16);
  r.w = __uint_as_float(u.y & 0xffff0000u);
  return r;
}

__device__ __forceinline__ void stage16(const u16* g, u16* lds_wave_base) {
  __builtin_amdgcn_global_load_lds((const __attribute__((address_space(1))) void*)g,
                                   (__attribute__((address_space(3))) void*)lds_wave_base,
                                   16, 0, 0);
}

// Stage a ROWSx64 bf16 tile (64-wide k-block kb) into LDS [row][64] with
// chunk swizzle: LDS chunk slot m of row r holds global k-chunk m ^ (r&7).
template <int ROWS>
__device__ __forceinline__ void stage_tile64(const u16* __restrict__ G, int ldK, int kb,
                                             u16* lds, int tid) {
#pragma unroll
  for (int r = 0; r < ROWS / 32; ++r) {
    int slot = r * 256 + tid;
    int row = slot >> 3;
    int kwg = (slot & 7) ^ (row & 7);
    stage16(G + (size_t)row * ldK + kb * 64 + kwg * 8,
            lds + (size_t)(r * 256 + (tid >> 6) * 64) * 8);
  }
}

// ---------------------------------------------------------------------------
// LayerNorm of one 512-row; 256 threads.
__device__ __forceinline__ void ln_row(const float* __restrict__ xr,
                                       const float* __restrict__ g,
                                       const float* __restrict__ bt,
                                       u16* __restrict__ yr, int tid, float* red) {
  float x0 = xr[tid], x1 = xr[tid + 256];
  float s = x0 + x1, ss = x0 * x0 + x1 * x1;
#pragma unroll
  for (int o = 32; o > 0; o >>= 1) { s += __shfl_xor(s, o); ss += __shfl_xor(ss, o); }
  if ((tid & 63) == 0) { red[tid >> 6] = s; red[4 + (tid >> 6)] = ss; }
  __syncthreads();
  float ts = red[0] + red[1] + red[2] + red[3];
  float tss = red[4] + red[5] + red[6] + red[7];
  float mu = ts * (1.f / 512.f);
  float var = tss * (1.f / 512.f) - mu * mu;
  float rstd = 1.0f / sqrtf(var + 1e-5f);
  yr[tid] = f2b((x0 - mu) * rstd * g[tid] + bt[tid]);
  yr[tid + 256] = f2b((x1 - mu) * rstd * g[tid + 256] + bt[tid + 256]);
}

// ---------------------------------------------------------------------------
// Prep: weight transposes f32->bf16 (0..3327), gate/bias pack (3328..3391),
// LN1 rows (3392..5439).
__global__ __launch_bounds__(256) void prep_weights(
    const float* __restrict__ Wk, const float* __restrict__ Wq,
    const float* __restrict__ Wv, const float* __restrict__ Wo,
    const float* __restrict__ Wps, const float* __restrict__ W1,
    const float* __restrict__ W2, const float* __restrict__ Wd,
    const float* __restrict__ Wgw, const float* __restrict__ Wgf,
    const float* __restrict__ bk, const float* __restrict__ bq,
    const float* __restrict__ bv, const float* __restrict__ bd,
    const float* __restrict__ bgw, const float* __restrict__ bgf,
    const float* __restrict__ x, const float* __restrict__ ln1g,
    const float* __restrict__ ln1b,
    u16* __restrict__ WTQ, u16* __restrict__ WTO, u16* __restrict__ WTPS,
    u16* __restrict__ WT1, u16* __restrict__ WT2, float* __restrict__ BQV,
    u16* __restrict__ XN) {
  int bid = blockIdx.x, tid = threadIdx.x;
  __shared__ float tile[32][33];
  __shared__ float red[8];
  if (bid < 3328) {
    const float* src;
    u16* dst;
    int C, rel, tiles_x;
    if (bid < 256)       { src = Wk;  dst = WTQ;           C = 512;  rel = bid;        tiles_x = 16; }
    else if (bid < 512)  { src = Wq;  dst = WTQ + 262144;  C = 512;  rel = bid - 256;  tiles_x = 16; }
    else if (bid < 768)  { src = Wv;  dst = WTQ + 524288;  C = 512;  rel = bid - 512;  tiles_x = 16; }
    else if (bid < 1024) { src = Wo;  dst = WTO;           C = 512;  rel = bid - 768;  tiles_x = 16; }
    else if (bid < 1280) { src = Wps; dst = WTPS;          C = 512;  rel = bid - 1024; tiles_x = 16; }
    else if (bid < 2304) { src = W1;  dst = WT1;           C = 2048; rel = bid - 1280; tiles_x = 64; }
    else                 { src = W2;  dst = WT2;           C = 512;  rel = bid - 2304; tiles_x = 16; }
    int R = (bid >= 1280 && bid < 2304) ? 512 : (bid >= 2304 ? 2048 : 512);
    int c0 = (rel % tiles_x) * 32, r0 = (rel / tiles_x) * 32;
    int tx = tid & 31, ty = tid >> 5;
#pragma unroll
    for (int i = 0; i < 4; ++i)
      tile[ty + i * 8][tx] = src[(size_t)(r0 + ty + i * 8) * C + c0 + tx];
    __syncthreads();
#pragma unroll
    for (int i = 0; i < 4; ++i)
      dst[(size_t)(c0 + ty + i * 8) * R + r0 + tx] = f2b(tile[tx][ty + i * 8]);
  } else if (bid < 3392) {
    int idx = (bid - 3328) * 256 + tid;
    const int stride = 64 * 256;
    for (int i = idx; i < 128 * 512; i += stride) {
      int local = i >> 9, k = i & 511;
      float v = 0.f;
      if (local < 8) v = Wd[k * 8 + local];
      else if (local < 16) v = Wgw[k * 8 + (local - 8)];
      else if (local < 24) v = Wgf[k * 8 + (local - 16)];
      WTQ[(size_t)(1536 + local) * 512 + k] = f2b(v);
    }
    for (int i = idx; i < 1664; i += stride) {
      float v = 0.f;
      if (i < 512) v = bk[i];
      else if (i < 1024) v = bq[i - 512];
      else if (i < 1536) v = bv[i - 1024];
      else if (i < 1544) v = bd[i - 1536];
      else if (i < 1552) v = bgw[i - 1544];
      else if (i < 1560) v = bgf[i - 1552];
      BQV[i] = v;
    }
  } else {
    int row = bid - 3392;
    ln_row(x + (size_t)row * 512, ln1g, ln1b, XN + (size_t)row * 512, tid, red);
  }
}

// Standalone LN2.
__global__ __launch_bounds__(256) void ln_f32(const float* __restrict__ X,
                                              const float* __restrict__ g,
                                              const float* __restrict__ bt,
                                              u16* __restrict__ Y) {
  __shared__ float red[8];
  ln_row(X + (size_t)blockIdx.x * 512, g, bt, Y + (size_t)blockIdx.x * 512,
         threadIdx.x, red);
}

// ---------------------------------------------------------------------------
// BMx64-tile, BK=64, 2-stage LDS GEMM, high occupancy (4-6 blocks/CU).
// 256 threads = 2x2 waves. EPI 0: outf=v; 1: outf=aux0+v+0.1*aux1;
// 2: outb=bf16(gelu(v)); 3: w=aux0+v,outf=w,outb=bf16(w);
// 4: outf=aux0+v, outf2=aux1+v.
template <int BM, int EPI>
__global__ __launch_bounds__(256, (BM == 64 ? 4 : 6)) void gemm2s(
    const u16* __restrict__ A, const u16* __restrict__ BT, const float* __restrict__ bias,
    float* __restrict__ outf, float* __restrict__ outf2, u16* __restrict__ outb,
    const float* __restrict__ aux0, const float* __restrict__ aux1, int M, int N, int K) {
  constexpr int MT = BM / 32;
  constexpr int S = BM / 32 + 2;  // DMA insts per thread per k-tile
  __shared__ __align__(16) u16 As[2][BM * 64];
  __shared__ __align__(16) u16 Bs[2][64 * 64];
  const int tid = threadIdx.x;
  const int lane = tid & 63, wave = tid >> 6;
  const int wm = wave >> 1, wn = wave & 1;
  const int m0 = blockIdx.y * BM, n0 = blockIdx.x * 64;
  floatx4 acc[MT][2] = {};
  const int fr = lane & 15, kq = lane >> 4;
  const int nk = K >> 6;
  const u16* Ab = A + (size_t)m0 * K;
  const u16* Bb = BT + (size_t)n0 * K;

  stage_tile64<BM>(Ab, K, 0, As[0], tid);
  stage_tile64<64>(Bb, K, 0, Bs[0], tid);

  for (int kb = 0; kb < nk; ++kb) {
    const int cur = kb & 1;
    if (kb + 1 < nk) {
      stage_tile64<BM>(Ab, K, kb + 1, As[cur ^ 1], tid);
      stage_tile64<64>(Bb, K, kb + 1, Bs[cur ^ 1], tid);
      if constexpr (S == 4) asm volatile("s_waitcnt vmcnt(4)" ::: "memory");
      else asm volatile("s_waitcnt vmcnt(3)" ::: "memory");
    } else {
      asm volatile("s_waitcnt vmcnt(0)" ::: "memory");
    }
    asm volatile("s_barrier" ::: "memory");

#pragma unroll
    for (int sub = 0; sub < 2; ++sub) {
      short8 af[MT], bf[2];
#pragma unroll
      for (int mt = 0; mt < MT; ++mt) {
        int row = wm * (BM / 2) + mt * 16 + fr;
        int c = sub * 4 + kq;
        af[mt] = *(const short8*)&As[cur][row * 64 + ((c ^ (row & 7)) << 3)];
      }
#pragma unroll
      for (int nt = 0; nt < 2; ++nt) {
        int row = wn * 32 + nt * 16 + fr;
        int c = sub * 4 + kq;
        bf[nt] = *(const short8*)&Bs[cur][row * 64 + ((c ^ (row & 7)) << 3)];
      }
#pragma unroll
      for (int mt = 0; mt < MT; ++mt)
#pragma unroll
        for (int nt = 0; nt < 2; ++nt)
          acc[mt][nt] =
              __builtin_amdgcn_mfma_f32_16x16x32_bf16(af[mt], bf[nt], acc[mt][nt], 0, 0, 0);
    }
    asm volatile("s_waitcnt lgkmcnt(0)" ::: "memory");
    asm volatile("s_barrier" ::: "memory");
  }

  const int col = lane & 15;
  const int rbase = (lane >> 4) * 4;
#pragma unroll
  for (int nt = 0; nt < 2; ++nt) {
    int gc = n0 + wn * 32 + nt * 16 + col;
    float bvv = bias[gc];
#pragma unroll
    for (int mt = 0; mt < MT; ++mt) {
      int gr = m0 + wm * (BM / 2) + mt * 16 + rbase;
#pragma unroll
      for (int r = 0; r < 4; ++r) {
        size_t idx = (size_t)(gr + r) * N + gc;
        float v = acc[mt][nt][r] + bvv;
        if constexpr (EPI == 0) {
          outf[idx] = v;
        } else if constexpr (EPI == 1) {
          outf[idx] = aux0[idx] + v + 0.1f * aux1[idx];
        } else if constexpr (EPI == 2) {
          outb[idx] = f2b(0.5f * v * (1.f + erff(v * 0.70710678118654752f)));
        } else if constexpr (EPI == 3) {
          float w = aux0[idx] + v;
          outf[idx] = w;
          outb[idx] = f2b(w);
        } else {
          outf[idx] = aux0[idx] + v;
          outf2[idx] = aux1[idx] + v;
        }
      }
    }
  }
}

// ---------------------------------------------------------------------------
// Per-token epilogue of the QKV+gates GEMM.
__global__ __launch_bounds__(512) void post_qkvg(const float* __restrict__ C0,
                                                 u16* __restrict__ KB, u16* __restrict__ QB,
                                                 u16* __restrict__ VG,
                                                 float* __restrict__ DEC) {
  int tok = blockIdx.x;
  int b = tok >> 10, t = tok & 1023;
  int tid = threadIdx.x;
  int h = tid >> 6, d = tid & 63;
  const float* row = C0 + (size_t)tok * 1664;

  float dl = row[1536 + h], gwl = row[1544 + h], gfl = row[1552 + h];
  float dd = dl > 20.f ? dl : log1pf(expf(dl));
  float sw = 1.f / (1.f + expf(-gwl));
  float gw = sw * sw;
  float sf = 1.f / (1.f + expf(-gfl));
  float gf = 1.f - sf * sf;

  size_t obase = ((size_t)(b * 8 + h) * 1024 + t) * 64 + d;

  float kx = row[h * 64 + d];
  float ssk = kx * kx;
#pragma unroll
  for (int o = 32; o > 0; o >>= 1) ssk += __shfl_xor(ssk, o);
  KB[obase] = f2b(kx / fmaxf(sqrtf(ssk), 1e-12f));

  float qx = row[512 + h * 64 + d];
  float ssq = qx * qx;
#pragma unroll
  for (int o = 32; o > 0; o >>= 1) ssq += __shfl_xor(ssq, o);
  QB[obase] = f2b(qx / fmaxf(sqrtf(ssq), 1e-12f));

  float vx = tanhf(row[1024 + h * 64 + d]);
  VG[obase] = f2b(vx * (dd * gw));

  if (d == 0)
    DEC[(size_t)(b * 8 + h) * 1024 + t] = fminf(fmaxf(dd * gf, 1e-6f), 0.999f);
}

// Cumulative log-decay per (b,h); w_t = c/(c+1e-8), c = exp(Lcum).
__global__ void logcum(const float* __restrict__ DEC, float* __restrict__ LC,
                       float* __restrict__ WW) {
  int bh = blockIdx.x;
  int lane = threadIdx.x;  // 64
  size_t base = (size_t)bh * 1024 + lane * 16;
  float loc[16];
  float run = 0.f;
#pragma unroll
  for (int i = 0; i < 16; ++i) { run += logf(DEC[base + i]); loc[i] = run; }
  float x = run;
#pragma unroll
  for (int o = 1; o < 64; o <<= 1) {
    float v = __shfl_up(x, o);
    if (lane >= o) x += v;
  }
  float excl = x - run;
#pragma unroll
  for (int i = 0; i < 16; ++i) {
    float L = excl + loc[i];
    LC[base + i] = L;
    float c = expf(L);
    WW[base + i] = c / (c + 1e-8f);
  }
}

// ---------------------------------------------------------------------------
// Scan phase 1: per (chunk,h,b) local scan of CT=32 steps with zero init.
// 512 blocks = 2 blocks/CU.
__global__ __launch_bounds__(256, 2) void scan_phase1(
    const u16* __restrict__ KB, const u16* __restrict__ QB, const u16* __restrict__ VG,
    const float* __restrict__ DEC, const float* __restrict__ WW,
    float* __restrict__ RP, float* __restrict__ SF) {
  int chunk = blockIdx.x, h = blockIdx.y, b = blockIdx.z;
  int bh = b * 8 + h;
  int t0 = chunk * 32;
  __shared__ __align__(16) float sk[2048], sq[2048], sv[2048];
  __shared__ float lsa[32], lsw[32];
  int tid = threadIdx.x;

  const u16* gk = KB + ((size_t)bh * 1024 + t0) * 64;
  const u16* gq = QB + ((size_t)bh * 1024 + t0) * 64;
  const u16* gv = VG + ((size_t)bh * 1024 + t0) * 64;
#pragma unroll
  for (int r = 0; r < 2; ++r) {
    int f = (r * 256 + tid) * 4;
    *(float4*)&sk[f] = b4_to_f4(*(const uint2*)(gk + f));
    *(float4*)&sq[f] = b4_to_f4(*(const uint2*)(gq + f));
    *(float4*)&sv[f] = b4_to_f4(*(const uint2*)(gv + f));
  }
  if (tid < 32) {
    lsa[tid] = DEC[(size_t)bh * 1024 + t0 + tid];
    lsw[tid] = WW[(size_t)bh * 1024 + t0 + tid];
  }
  __syncthreads();

  int i = tid >> 2, j0 = (tid & 3) * 16;
  float s[16];
#pragma unroll
  for (int z = 0; z < 16; ++z) s[z] = 0.f;

  for (int t = 0; t < 32; ++t) {
    float a = lsa[t], w = lsw[t];
    float wv = w * sv[t * 64 + i];
    float r = 0.f;
#pragma unroll
    for (int u4 = 0; u4 < 4; ++u4) {
      float4 kv = *(const float4*)&sk[t * 64 + j0 + u4 * 4];
      float4 qv = *(const float4*)&sq[t * 64 + j0 + u4 * 4];
      s[u4 * 4 + 0] = fmaf(a, s[u4 * 4 + 0], wv * kv.x); r = fmaf(s[u4 * 4 + 0], qv.x, r);
      s[u4 * 4 + 1] = fmaf(a, s[u4 * 4 + 1], wv * kv.y); r = fmaf(s[u4 * 4 + 1], qv.y, r);
      s[u4 * 4 + 2] = fmaf(a, s[u4 * 4 + 2], wv * kv.z); r = fmaf(s[u4 * 4 + 2], qv.z, r);
      s[u4 * 4 + 3] = fmaf(a, s[u4 * 4 + 3], wv * kv.w); r = fmaf(s[u4 * 4 + 3], qv.w, r);
    }
    r += __shfl_xor(r, 1);
    r += __shfl_xor(r, 2);
    if ((tid & 3) == 0)
      RP[((size_t)(b * 1024 + t0 + t) * 8 + h) * 64 + i] = r;
  }

  float* Sf = SF + ((size_t)bh * 32 + chunk) * 4096 + i * 64 + j0;
#pragma unroll
  for (int u4 = 0; u4 < 4; ++u4) {
    float4 v;
    v.x = s[u4 * 4 + 0]; v.y = s[u4 * 4 + 1]; v.z = s[u4 * 4 + 2]; v.w = s[u4 * 4 + 3];
    *(float4*)&Sf[u4 * 4] = v;
  }
}

// Scan phase 2: cross-chunk combine over 32 chunks, fully parallel (256 blocks).
__global__ __launch_bounds__(256) void scan_phase2p(const float* __restrict__ SF,
                                                    const float* __restrict__ LC,
                                                    float* __restrict__ SI,
                                                    float* __restrict__ next_mem) {
  int bh = blockIdx.x >> 4;
  int e = (blockIdx.x & 15) * 256 + threadIdx.x;
  float s = 0.f;
  for (int c = 0; c < 32; ++c) {
    SI[((size_t)bh * 32 + c) * 4096 + e] = s;
    float Lend = LC[(size_t)bh * 1024 + c * 32 + 31];
    float Lpre = c ? LC[(size_t)bh * 1024 + c * 32 - 1] : 0.f;
    float P = expf(Lend - Lpre);
    s = fmaf(P, s, SF[((size_t)bh * 32 + c) * 4096 + e]);
  }
  next_mem[(size_t)bh * 4096 + e] = s;
}

// Scan phase 3: add inter-chunk contribution p_t*(Sinit @ q_t); bf16 readout.
__global__ __launch_bounds__(256, 2) void scan_phase3(
    const u16* __restrict__ QB, const float* __restrict__ SI, const float* __restrict__ LC,
    const float* __restrict__ RP, u16* __restrict__ AB) {
  int chunk = blockIdx.x, h = blockIdx.y, b = blockIdx.z;
  int bh = b * 8 + h;
  int t0 = chunk * 32;
  __shared__ __align__(16) float sq[2048];
  __shared__ float sL[32];
  int tid = threadIdx.x;

  const u16* gq = QB + ((size_t)bh * 1024 + t0) * 64;
#pragma unroll
  for (int r = 0; r < 2; ++r) {
    int f = (r * 256 + tid) * 4;
    *(float4*)&sq[f] = b4_to_f4(*(const uint2*)(gq + f));
  }
  if (tid < 32) sL[tid] = LC[(size_t)bh * 1024 + t0 + tid];
  __syncthreads();

  float Lpre = chunk ? LC[(size_t)bh * 1024 + t0 - 1] : 0.f;
  int i = tid >> 2, j0 = (tid & 3) * 16;
  const float* Si = SI + ((size_t)bh * 32 + chunk) * 4096 + i * 64 + j0;
  float S[16];
#pragma unroll
  for (int u4 = 0; u4 < 4; ++u4) {
    float4 v = *(const float4*)&Si[u4 * 4];
    S[u4 * 4 + 0] = v.x; S[u4 * 4 + 1] = v.y; S[u4 * 4 + 2] = v.z; S[u4 * 4 + 3] = v.w;
  }

  for (int t = 0; t < 32; ++t) {
    float p = expf(sL[t] - Lpre);
    float r = 0.f;
#pragma unroll
    for (int u4 = 0; u4 < 4; ++u4) {
      float4 qv = *(const float4*)&sq[t * 64 + j0 + u4 * 4];
      r = fmaf(S[u4 * 4 + 0], qv.x, r);
      r = fmaf(S[u4 * 4 + 1], qv.y, r);
      r = fmaf(S[u4 * 4 + 2], qv.z, r);
      r = fmaf(S[u4 * 4 + 3], qv.w, r);
    }
    r += __shfl_xor(r, 1);
    r += __shfl_xor(r, 2);
    if ((tid & 3) == 0) {
      size_t gi = ((size_t)(b * 1024 + t0 + t) * 8 + h) * 64 + i;
      AB[gi] = f2b(RP[gi] + p * r);
    }
  }
}

// ---------------------------------------------------------------------------
extern "C" void kernel_launch(void* const* d_in, const int* in_sizes, int n_in,
                              void* d_out, int out_size, void* d_ws, size_t ws_size,
                              hipStream_t stream) {
  const float* x = (const float*)d_in[0];
  const float* bmin = (const float*)d_in[1];
  const float* bmax = (const float*)d_in[2];
  const float* motif = (const float*)d_in[3];
  const float* Wk = (const float*)d_in[4];
  const float* bk = (const float*)d_in[5];
  const float* Wq = (const float*)d_in[6];
  const float* bq = (const float*)d_in[7];
  const float* Wv = (const float*)d_in[8];
  const float* bv = (const float*)d_in[9];
  const float* Wo = (const float*)d_in[10];
  const float* bo = (const float*)d_in[11];
  const float* Wd = (const float*)d_in[12];
  const float* bd = (const float*)d_in[13];
  const float* Wgw = (const float*)d_in[14];
  const float* bgw = (const float*)d_in[15];
  const float* Wgf = (const float*)d_in[16];
  const float* bgf = (const float*)d_in[17];
  const float* Wps = (const float*)d_in[18];
  const float* bps = (const float*)d_in[19];
  const float* ln1g = (const float*)d_in[20];
  const float* ln1b = (const float*)d_in[21];
  const float* ln2g = (const float*)d_in[22];
  const float* ln2b = (const float*)d_in[23];
  const float* W1 = (const float*)d_in[24];
  const float* b1 = (const float*)d_in[25];
  const float* W2 = (const float*)d_in[26];
  const float* b2 = (const float*)d_in[27];

  char* ws = (char*)d_ws;
  u16* WTQ = (u16*)(ws + 0);
  u16* WTO = (u16*)(ws + 1703936);
  u16* WT1 = (u16*)(ws + 2228224);
  u16* WT2 = (u16*)(ws + 4325376);
  u16* WTPS = (u16*)(ws + 6422528);
  float* BQV = (float*)(ws + 6946816);
  u16* XN = (u16*)(ws + 6953984);       // -> 9051136
  float* C0 = (float*)(ws + 9051136);   // -> 22682624
  u16* KB = (u16*)(ws + 22682624);      // -> 24779776
  u16* QB = (u16*)(ws + 24779776);      // -> 26876928
  u16* VG = (u16*)(ws + 26876928);      // -> 28974080
  float* DEC = (float*)(ws + 28974080); // -> 29039616
  float* LC = (float*)(ws + 29039616);  // -> 29105152
  float* WW = (float*)(ws + 29105152);  // -> 29170688
  float* RP = (float*)(ws + 29170688);  // -> 33364992
  float* SF = (float*)(ws + 33364992);  // 8MB -> 41753600
  float* SI = (float*)(ws + 41753600);  // 8MB -> 50142208
  u16* AB = (u16*)(ws + 9051136);       // aliases C0 (dead after post_qkvg)
  float* X2 = (float*)(ws + 11148288);  // -> 15342592
  u16* HB = (u16*)(ws + 15342592);      // -> 17439744
  u16* MID = (u16*)(ws + 17439744);     // -> 25828352 (KB/QB dead by FFN1)
  u16* X3B = (u16*)(ws + 26876928);     // aliases VG (dead after scan1)

  float* out0 = (float*)d_out;
  float* out1 = out0 + 1048576;
  float* out2 = out0 + 1114112;
  float* out3 = out0 + 2162688;

  prep_weights<<<5440, 256, 0, stream>>>(Wk, Wq, Wv, Wo, Wps, W1, W2, Wd, Wgw, Wgf,
                                         bk, bq, bv, bd, bgw, bgf, x, ln1g, ln1b,
                                         WTQ, WTO, WTPS, WT1, WT2, BQV, XN);
  gemm2s<64, 0><<<dim3(26, 32), 256, 0, stream>>>(XN, WTQ, BQV, C0, nullptr, nullptr,
                                                  nullptr, nullptr, 2048, 1664, 512);
  post_qkvg<<<2048, 512, 0, stream>>>(C0, KB, QB, VG, DEC);
  logcum<<<16, 64, 0, stream>>>(DEC, LC, WW);
  scan_phase1<<<dim3(32, 8, 2), 256, 0, stream>>>(KB, QB, VG, DEC, WW, RP, SF);
  scan_phase2p<<<256, 256, 0, stream>>>(SF, LC, SI, out1);
  scan_phase3<<<dim3(32, 8, 2), 256, 0, stream>>>(QB, SI, LC, RP, AB);

  gemm2s<32, 1><<<dim3(8, 64), 256, 0, stream>>>(AB, WTO, bo, X2, nullptr, nullptr,
                                                 x, motif, 2048, 512, 512);
  ln_f32<<<2048, 256, 0, stream>>>(X2, ln2g, ln2b, HB);
  gemm2s<64, 2><<<dim3(32, 32), 256, 0, stream>>>(HB, WT1, b1, nullptr, nullptr, MID,
                                                  nullptr, nullptr, 2048, 2048, 512);
  gemm2s<32, 3><<<dim3(8, 64), 256, 0, stream>>>(MID, WT2, b2, out0, nullptr, X3B,
                                                 X2, nullptr, 2048, 512, 2048);
  gemm2s<32, 4><<<dim3(8, 64), 256, 0, stream>>>(X3B, WTPS, bps, out2, out3, nullptr,
                                                 bmin, bmax, 2048, 512, 512);
}

// Round 9
// 230.304 us; speedup vs baseline: 2.5696x; 1.0189x over previous
//
#include <hip/hip_runtime.h>

// HoloGraphBlockV7 — round 9: fused QKV epilogue (l2norm/tanh/gates in the
// GEMM epilogue; the 13.6MB f32 C0 round-trip is gone), gates+logcum merged
// into one small kernel, v-gating folded into scan_phase1. 12 -> 11 dispatches.

typedef unsigned short u16;
typedef unsigned int u32;
typedef __attribute__((ext_vector_type(8))) short short8;
typedef __attribute__((ext_vector_type(4))) float floatx4;

__device__ __forceinline__ float b2f(u16 u) {
  u32 x = ((u32)u) << 16;
  return __uint_as_float(x);
}
__device__ __forceinline__ u16 f2b(float f) {
  u32 x = __float_as_uint(f);
  u32 r = (x + 0x7fffu + ((x >> 16) & 1u)) >> 16;
  return (u16)r;
}
__device__ __forceinline__ float4 b4_to_f4(uint2 u) {
  float4 r;
  r.x = __uint_as_float((u.x & 0xffffu) << 16);
  r.y = __uint_as_float(u.x & 0xffff0000u);
  r.z = __uint_as_float((u.y & 0xffffu) << 16);
  r.w = __uint_as_float(u.y & 0xffff0000u);
  return r;
}

__device__ __forceinline__ void stage16(const u16* g, u16* lds_wave_base) {
  __builtin_amdgcn_global_load_lds((const __attribute__((address_space(1))) void*)g,
                                   (__attribute__((address_space(3))) void*)lds_wave_base,
                                   16, 0, 0);
}

// Stage a ROWSx64 bf16 tile (64-wide k-block kb) into LDS [row][64] with
// chunk swizzle: LDS chunk slot m of row r holds global k-chunk m ^ (r&7).
template <int ROWS>
__device__ __forceinline__ void stage_tile64(const u16* __restrict__ G, int ldK, int kb,
                                             u16* lds, int tid) {
#pragma unroll
  for (int r = 0; r < ROWS / 32; ++r) {
    int slot = r * 256 + tid;
    int row = slot >> 3;
    int kwg = (slot & 7) ^ (row & 7);
    stage16(G + (size_t)row * ldK + kb * 64 + kwg * 8,
            lds + (size_t)(r * 256 + (tid >> 6) * 64) * 8);
  }
}

// ---------------------------------------------------------------------------
// LayerNorm of one 512-row; 256 threads.
__device__ __forceinline__ void ln_row(const float* __restrict__ xr,
                                       const float* __restrict__ g,
                                       const float* __restrict__ bt,
                                       u16* __restrict__ yr, int tid, float* red) {
  float x0 = xr[tid], x1 = xr[tid + 256];
  float s = x0 + x1, ss = x0 * x0 + x1 * x1;
#pragma unroll
  for (int o = 32; o > 0; o >>= 1) { s += __shfl_xor(s, o); ss += __shfl_xor(ss, o); }
  if ((tid & 63) == 0) { red[tid >> 6] = s; red[4 + (tid >> 6)] = ss; }
  __syncthreads();
  float ts = red[0] + red[1] + red[2] + red[3];
  float tss = red[4] + red[5] + red[6] + red[7];
  float mu = ts * (1.f / 512.f);
  float var = tss * (1.f / 512.f) - mu * mu;
  float rstd = 1.0f / sqrtf(var + 1e-5f);
  yr[tid] = f2b((x0 - mu) * rstd * g[tid] + bt[tid]);
  yr[tid + 256] = f2b((x1 - mu) * rstd * g[tid + 256] + bt[tid + 256]);
}

// ---------------------------------------------------------------------------
// Prep: weight transposes f32->bf16 (0..3327), gate/bias pack (3328..3391),
// LN1 rows (3392..5439).
__global__ __launch_bounds__(256) void prep_weights(
    const float* __restrict__ Wk, const float* __restrict__ Wq,
    const float* __restrict__ Wv, const float* __restrict__ Wo,
    const float* __restrict__ Wps, const float* __restrict__ W1,
    const float* __restrict__ W2, const float* __restrict__ Wd,
    const float* __restrict__ Wgw, const float* __restrict__ Wgf,
    const float* __restrict__ bk, const float* __restrict__ bq,
    const float* __restrict__ bv, const float* __restrict__ bd,
    const float* __restrict__ bgw, const float* __restrict__ bgf,
    const float* __restrict__ x, const float* __restrict__ ln1g,
    const float* __restrict__ ln1b,
    u16* __restrict__ WTQ, u16* __restrict__ WTO, u16* __restrict__ WTPS,
    u16* __restrict__ WT1, u16* __restrict__ WT2, float* __restrict__ BQV,
    u16* __restrict__ XN) {
  int bid = blockIdx.x, tid = threadIdx.x;
  __shared__ float tile[32][33];
  __shared__ float red[8];
  if (bid < 3328) {
    const float* src;
    u16* dst;
    int C, rel, tiles_x;
    if (bid < 256)       { src = Wk;  dst = WTQ;           C = 512;  rel = bid;        tiles_x = 16; }
    else if (bid < 512)  { src = Wq;  dst = WTQ + 262144;  C = 512;  rel = bid - 256;  tiles_x = 16; }
    else if (bid < 768)  { src = Wv;  dst = WTQ + 524288;  C = 512;  rel = bid - 512;  tiles_x = 16; }
    else if (bid < 1024) { src = Wo;  dst = WTO;           C = 512;  rel = bid - 768;  tiles_x = 16; }
    else if (bid < 1280) { src = Wps; dst = WTPS;          C = 512;  rel = bid - 1024; tiles_x = 16; }
    else if (bid < 2304) { src = W1;  dst = WT1;           C = 2048; rel = bid - 1280; tiles_x = 64; }
    else                 { src = W2;  dst = WT2;           C = 512;  rel = bid - 2304; tiles_x = 16; }
    int R = (bid >= 1280 && bid < 2304) ? 512 : (bid >= 2304 ? 2048 : 512);
    int c0 = (rel % tiles_x) * 32, r0 = (rel / tiles_x) * 32;
    int tx = tid & 31, ty = tid >> 5;
#pragma unroll
    for (int i = 0; i < 4; ++i)
      tile[ty + i * 8][tx] = src[(size_t)(r0 + ty + i * 8) * C + c0 + tx];
    __syncthreads();
#pragma unroll
    for (int i = 0; i < 4; ++i)
      dst[(size_t)(c0 + ty + i * 8) * R + r0 + tx] = f2b(tile[tx][ty + i * 8]);
  } else if (bid < 3392) {
    int idx = (bid - 3328) * 256 + tid;
    const int stride = 64 * 256;
    for (int i = idx; i < 128 * 512; i += stride) {
      int local = i >> 9, k = i & 511;
      float v = 0.f;
      if (local < 8) v = Wd[k * 8 + local];
      else if (local < 16) v = Wgw[k * 8 + (local - 8)];
      else if (local < 24) v = Wgf[k * 8 + (local - 16)];
      WTQ[(size_t)(1536 + local) * 512 + k] = f2b(v);
    }
    for (int i = idx; i < 1664; i += stride) {
      float v = 0.f;
      if (i < 512) v = bk[i];
      else if (i < 1024) v = bq[i - 512];
      else if (i < 1536) v = bv[i - 1024];
      else if (i < 1544) v = bd[i - 1536];
      else if (i < 1552) v = bgw[i - 1544];
      else if (i < 1560) v = bgf[i - 1552];
      BQV[i] = v;
    }
  } else {
    int row = bid - 3392;
    ln_row(x + (size_t)row * 512, ln1g, ln1b, XN + (size_t)row * 512, tid, red);
  }
}

// Standalone LN2.
__global__ __launch_bounds__(256) void ln_f32(const float* __restrict__ X,
                                              const float* __restrict__ g,
                                              const float* __restrict__ bt,
                                              u16* __restrict__ Y) {
  __shared__ float red[8];
  ln_row(X + (size_t)blockIdx.x * 512, g, bt, Y + (size_t)blockIdx.x * 512,
         threadIdx.x, red);
}

// ---------------------------------------------------------------------------
// BMx64-tile, BK=64, 2-stage LDS GEMM, high occupancy. 256 threads = 2x2 waves.
// EPI 1: outf = aux0+v+0.1*aux1
// EPI 2: outb = bf16(gelu(v))
// EPI 3: w = aux0+v; outf = w; outb = bf16(w)
// EPI 4: outf = aux0+v; outf2 = aux1+v
// EPI 5 (QKV, BM=64, N=1664): n-tile sections: [0,512) l2norm->outb(KB);
//   [512,1024) l2norm->outb2(QB); [1024,1536) tanh->outb3(VB);
//   [1536,1664) raw f32 -> outf(G0, 2048x128).
template <int BM, int EPI>
__global__ __launch_bounds__(256, (BM == 64 ? 4 : 6)) void gemm2s(
    const u16* __restrict__ A, const u16* __restrict__ BT, const float* __restrict__ bias,
    float* __restrict__ outf, float* __restrict__ outf2, u16* __restrict__ outb,
    u16* __restrict__ outb2, u16* __restrict__ outb3,
    const float* __restrict__ aux0, const float* __restrict__ aux1, int M, int N, int K) {
  constexpr int MT = BM / 32;
  constexpr int S = BM / 32 + 2;  // DMA insts per thread per k-tile
  __shared__ __align__(16) u16 As[2][BM * 64];
  __shared__ __align__(16) u16 Bs[2][64 * 64];
  __shared__ float ssb[2][BM];
  const int tid = threadIdx.x;
  const int lane = tid & 63, wave = tid >> 6;
  const int wm = wave >> 1, wn = wave & 1;
  const int m0 = blockIdx.y * BM, n0 = blockIdx.x * 64;
  floatx4 acc[MT][2] = {};
  const int fr = lane & 15, kq = lane >> 4;
  const int nk = K >> 6;
  const u16* Ab = A + (size_t)m0 * K;
  const u16* Bb = BT + (size_t)n0 * K;

  stage_tile64<BM>(Ab, K, 0, As[0], tid);
  stage_tile64<64>(Bb, K, 0, Bs[0], tid);

  for (int kb = 0; kb < nk; ++kb) {
    const int cur = kb & 1;
    if (kb + 1 < nk) {
      stage_tile64<BM>(Ab, K, kb + 1, As[cur ^ 1], tid);
      stage_tile64<64>(Bb, K, kb + 1, Bs[cur ^ 1], tid);
      if constexpr (S == 4) asm volatile("s_waitcnt vmcnt(4)" ::: "memory");
      else asm volatile("s_waitcnt vmcnt(3)" ::: "memory");
    } else {
      asm volatile("s_waitcnt vmcnt(0)" ::: "memory");
    }
    asm volatile("s_barrier" ::: "memory");

#pragma unroll
    for (int sub = 0; sub < 2; ++sub) {
      short8 af[MT], bf[2];
#pragma unroll
      for (int mt = 0; mt < MT; ++mt) {
        int row = wm * (BM / 2) + mt * 16 + fr;
        int c = sub * 4 + kq;
        af[mt] = *(const short8*)&As[cur][row * 64 + ((c ^ (row & 7)) << 3)];
      }
#pragma unroll
      for (int nt = 0; nt < 2; ++nt) {
        int row = wn * 32 + nt * 16 + fr;
        int c = sub * 4 + kq;
        bf[nt] = *(const short8*)&Bs[cur][row * 64 + ((c ^ (row & 7)) << 3)];
      }
#pragma unroll
      for (int mt = 0; mt < MT; ++mt)
#pragma unroll
        for (int nt = 0; nt < 2; ++nt)
          acc[mt][nt] =
              __builtin_amdgcn_mfma_f32_16x16x32_bf16(af[mt], bf[nt], acc[mt][nt], 0, 0, 0);
    }
    asm volatile("s_waitcnt lgkmcnt(0)" ::: "memory");
    asm volatile("s_barrier" ::: "memory");
  }

  const int col = lane & 15;
  const int rbase = (lane >> 4) * 4;

  // v (acc + bias), per (mt, nt, r)
  float vv[MT][2][4];
#pragma unroll
  for (int nt = 0; nt < 2; ++nt) {
    int gc = n0 + wn * 32 + nt * 16 + col;
    float bvv = bias[gc];
#pragma unroll
    for (int mt = 0; mt < MT; ++mt)
#pragma unroll
      for (int r = 0; r < 4; ++r) vv[mt][nt][r] = acc[mt][nt][r] + bvv;
  }

  if constexpr (EPI == 5) {
    const int sec = n0 >> 9;              // 0 K, 1 Q, 2 V, 3 gates
    const int h = (n0 & 511) >> 6;        // head (BN=64 == head size)
    if (sec == 3) {
#pragma unroll
      for (int nt = 0; nt < 2; ++nt) {
        int gcl = (n0 - 1536) + wn * 32 + nt * 16 + col;
#pragma unroll
        for (int mt = 0; mt < MT; ++mt) {
          int gr = m0 + wm * (BM / 2) + mt * 16 + rbase;
#pragma unroll
          for (int r = 0; r < 4; ++r)
            outf[(size_t)(gr + r) * 128 + gcl] = vv[mt][nt][r];
        }
      }
    } else if (sec == 2) {
#pragma unroll
      for (int nt = 0; nt < 2; ++nt) {
        int d = wn * 32 + nt * 16 + col;
#pragma unroll
        for (int mt = 0; mt < MT; ++mt) {
          int gr = m0 + wm * (BM / 2) + mt * 16 + rbase;
#pragma unroll
          for (int r = 0; r < 4; ++r) {
            int tok = gr + r;
            int bh = (tok >> 10) * 8 + h;
            outb3[((size_t)bh * 1024 + (tok & 1023)) * 64 + d] = f2b(tanhf(vv[mt][nt][r]));
          }
        }
      }
    } else {
      // l2norm over the head's 64 cols: wave-local 32-col sum + LDS exchange.
#pragma unroll
      for (int mt = 0; mt < MT; ++mt) {
#pragma unroll
        for (int r = 0; r < 4; ++r) {
          float ss = vv[mt][0][r] * vv[mt][0][r] + vv[mt][1][r] * vv[mt][1][r];
          ss += __shfl_xor(ss, 1);
          ss += __shfl_xor(ss, 2);
          ss += __shfl_xor(ss, 4);
          ss += __shfl_xor(ss, 8);
          if ((lane & 15) == 0)
            ssb[wn][wm * (BM / 2) + mt * 16 + rbase + r] = ss;
        }
      }
      __syncthreads();
      u16* dst = (sec == 0) ? outb : outb2;
#pragma unroll
      for (int mt = 0; mt < MT; ++mt) {
#pragma unroll
        for (int r = 0; r < 4; ++r) {
          int br = wm * (BM / 2) + mt * 16 + rbase + r;
          float tot = ssb[0][br] + ssb[1][br];
          float rs = 1.0f / fmaxf(sqrtf(tot), 1e-12f);
          int tok = m0 + br;
          int bh = (tok >> 10) * 8 + h;
          size_t base = ((size_t)bh * 1024 + (tok & 1023)) * 64;
#pragma unroll
          for (int nt = 0; nt < 2; ++nt) {
            int d = wn * 32 + nt * 16 + col;
            dst[base + d] = f2b(vv[mt][nt][r] * rs);
          }
        }
      }
    }
  } else {
#pragma unroll
    for (int nt = 0; nt < 2; ++nt) {
      int gc = n0 + wn * 32 + nt * 16 + col;
#pragma unroll
      for (int mt = 0; mt < MT; ++mt) {
        int gr = m0 + wm * (BM / 2) + mt * 16 + rbase;
#pragma unroll
        for (int r = 0; r < 4; ++r) {
          size_t idx = (size_t)(gr + r) * N + gc;
          float v = vv[mt][nt][r];
          if constexpr (EPI == 1) {
            outf[idx] = aux0[idx] + v + 0.1f * aux1[idx];
          } else if constexpr (EPI == 2) {
            outb[idx] = f2b(0.5f * v * (1.f + erff(v * 0.70710678118654752f)));
          } else if constexpr (EPI == 3) {
            float w = aux0[idx] + v;
            outf[idx] = w;
            outb[idx] = f2b(w);
          } else if constexpr (EPI == 4) {
            outf[idx] = aux0[idx] + v;
            outf2[idx] = aux1[idx] + v;
          }
        }
      }
    }
  }
}

// ---------------------------------------------------------------------------
// Gates (softplus/sigmoid) + DEC + SVG + serial log-cumsum, one kernel.
// grid = 16 (b,h); 256 threads.
__global__ __launch_bounds__(256) void gates_logcum(
    const float* __restrict__ G0, float* __restrict__ DEC, float* __restrict__ SVG,
    float* __restrict__ LC, float* __restrict__ WW) {
  int bh = blockIdx.x;
  int b = bh >> 3, h = bh & 7;
  int tid = threadIdx.x;
  __shared__ float ldec[1024];
#pragma unroll
  for (int tt = 0; tt < 4; ++tt) {
    int t = tt * 256 + tid;
    size_t tok = (size_t)b * 1024 + t;
    float dl = G0[tok * 128 + h];
    float gwl = G0[tok * 128 + 8 + h];
    float gfl = G0[tok * 128 + 16 + h];
    float dd = dl > 20.f ? dl : log1pf(expf(dl));
    float sw = 1.f / (1.f + expf(-gwl));
    float gw = sw * sw;
    float sf = 1.f / (1.f + expf(-gfl));
    float gf = 1.f - sf * sf;
    float dec = fminf(fmaxf(dd * gf, 1e-6f), 0.999f);
    ldec[t] = dec;
    DEC[(size_t)bh * 1024 + t] = dec;
    SVG[(size_t)bh * 1024 + t] = dd * gw;
  }
  __syncthreads();
  if (tid < 64) {
    int lane = tid;
    size_t base = (size_t)bh * 1024 + lane * 16;
    float loc[16];
    float run = 0.f;
#pragma unroll
    for (int i = 0; i < 16; ++i) { run += logf(ldec[lane * 16 + i]); loc[i] = run; }
    float x = run;
#pragma unroll
    for (int o = 1; o < 64; o <<= 1) {
      float v = __shfl_up(x, o);
      if (lane >= o) x += v;
    }
    float excl = x - run;
#pragma unroll
    for (int i = 0; i < 16; ++i) {
      float L = excl + loc[i];
      LC[base + i] = L;
      float c = expf(L);
      WW[base + i] = c / (c + 1e-8f);
    }
  }
}

// ---------------------------------------------------------------------------
// Scan phase 1: per (chunk,h,b) local scan of 32 steps, zero init.
// v-gating (SVG) folded into the per-step weight.
__global__ __launch_bounds__(256, 2) void scan_phase1(
    const u16* __restrict__ KB, const u16* __restrict__ QB, const u16* __restrict__ VB,
    const float* __restrict__ DEC, const float* __restrict__ WW,
    const float* __restrict__ SVG, float* __restrict__ RP, float* __restrict__ SF) {
  int chunk = blockIdx.x, h = blockIdx.y, b = blockIdx.z;
  int bh = b * 8 + h;
  int t0 = chunk * 32;
  __shared__ __align__(16) float sk[2048], sq[2048], sv[2048];
  __shared__ float lsa[32], lsw[32];
  int tid = threadIdx.x;

  const u16* gk = KB + ((size_t)bh * 1024 + t0) * 64;
  const u16* gq = QB + ((size_t)bh * 1024 + t0) * 64;
  const u16* gv = VB + ((size_t)bh * 1024 + t0) * 64;
#pragma unroll
  for (int r = 0; r < 2; ++r) {
    int f = (r * 256 + tid) * 4;
    *(float4*)&sk[f] = b4_to_f4(*(const uint2*)(gk + f));
    *(float4*)&sq[f] = b4_to_f4(*(const uint2*)(gq + f));
    *(float4*)&sv[f] = b4_to_f4(*(const uint2*)(gv + f));
  }
  if (tid < 32) {
    size_t gi = (size_t)bh * 1024 + t0 + tid;
    lsa[tid] = DEC[gi];
    lsw[tid] = WW[gi] * SVG[gi];
  }
  __syncthreads();

  int i = tid >> 2, j0 = (tid & 3) * 16;
  float s[16];
#pragma unroll
  for (int z = 0; z < 16; ++z) s[z] = 0.f;

  for (int t = 0; t < 32; ++t) {
    float a = lsa[t], w = lsw[t];
    float wv = w * sv[t * 64 + i];
    float r = 0.f;
#pragma unroll
    for (int u4 = 0; u4 < 4; ++u4) {
      float4 kv = *(const float4*)&sk[t * 64 + j0 + u4 * 4];
      float4 qv = *(const float4*)&sq[t * 64 + j0 + u4 * 4];
      s[u4 * 4 + 0] = fmaf(a, s[u4 * 4 + 0], wv * kv.x); r = fmaf(s[u4 * 4 + 0], qv.x, r);
      s[u4 * 4 + 1] = fmaf(a, s[u4 * 4 + 1], wv * kv.y); r = fmaf(s[u4 * 4 + 1], qv.y, r);
      s[u4 * 4 + 2] = fmaf(a, s[u4 * 4 + 2], wv * kv.z); r = fmaf(s[u4 * 4 + 2], qv.z, r);
      s[u4 * 4 + 3] = fmaf(a, s[u4 * 4 + 3], wv * kv.w); r = fmaf(s[u4 * 4 + 3], qv.w, r);
    }
    r += __shfl_xor(r, 1);
    r += __shfl_xor(r, 2);
    if ((tid & 3) == 0)
      RP[((size_t)(b * 1024 + t0 + t) * 8 + h) * 64 + i] = r;
  }

  float* Sf = SF + ((size_t)bh * 32 + chunk) * 4096 + i * 64 + j0;
#pragma unroll
  for (int u4 = 0; u4 < 4; ++u4) {
    float4 v;
    v.x = s[u4 * 4 + 0]; v.y = s[u4 * 4 + 1]; v.z = s[u4 * 4 + 2]; v.w = s[u4 * 4 + 3];
    *(float4*)&Sf[u4 * 4] = v;
  }
}

// Scan phase 2: cross-chunk combine over 32 chunks, fully parallel (256 blocks).
__global__ __launch_bounds__(256) void scan_phase2p(const float* __restrict__ SF,
                                                    const float* __restrict__ LC,
                                                    float* __restrict__ SI,
                                                    float* __restrict__ next_mem) {
  int bh = blockIdx.x >> 4;
  int e = (blockIdx.x & 15) * 256 + threadIdx.x;
  float s = 0.f;
  for (int c = 0; c < 32; ++c) {
    SI[((size_t)bh * 32 + c) * 4096 + e] = s;
    float Lend = LC[(size_t)bh * 1024 + c * 32 + 31];
    float Lpre = c ? LC[(size_t)bh * 1024 + c * 32 - 1] : 0.f;
    float P = expf(Lend - Lpre);
    s = fmaf(P, s, SF[((size_t)bh * 32 + c) * 4096 + e]);
  }
  next_mem[(size_t)bh * 4096 + e] = s;
}

// Scan phase 3: add inter-chunk contribution p_t*(Sinit @ q_t); bf16 readout.
__global__ __launch_bounds__(256, 2) void scan_phase3(
    const u16* __restrict__ QB, const float* __restrict__ SI, const float* __restrict__ LC,
    const float* __restrict__ RP, u16* __restrict__ AB) {
  int chunk = blockIdx.x, h = blockIdx.y, b = blockIdx.z;
  int bh = b * 8 + h;
  int t0 = chunk * 32;
  __shared__ __align__(16) float sq[2048];
  __shared__ float sL[32];
  int tid = threadIdx.x;

  const u16* gq = QB + ((size_t)bh * 1024 + t0) * 64;
#pragma unroll
  for (int r = 0; r < 2; ++r) {
    int f = (r * 256 + tid) * 4;
    *(float4*)&sq[f] = b4_to_f4(*(const uint2*)(gq + f));
  }
  if (tid < 32) sL[tid] = LC[(size_t)bh * 1024 + t0 + tid];
  __syncthreads();

  float Lpre = chunk ? LC[(size_t)bh * 1024 + t0 - 1] : 0.f;
  int i = tid >> 2, j0 = (tid & 3) * 16;
  const float* Si = SI + ((size_t)bh * 32 + chunk) * 4096 + i * 64 + j0;
  float S[16];
#pragma unroll
  for (int u4 = 0; u4 < 4; ++u4) {
    float4 v = *(const float4*)&Si[u4 * 4];
    S[u4 * 4 + 0] = v.x; S[u4 * 4 + 1] = v.y; S[u4 * 4 + 2] = v.z; S[u4 * 4 + 3] = v.w;
  }

  for (int t = 0; t < 32; ++t) {
    float p = expf(sL[t] - Lpre);
    float r = 0.f;
#pragma unroll
    for (int u4 = 0; u4 < 4; ++u4) {
      float4 qv = *(const float4*)&sq[t * 64 + j0 + u4 * 4];
      r = fmaf(S[u4 * 4 + 0], qv.x, r);
      r = fmaf(S[u4 * 4 + 1], qv.y, r);
      r = fmaf(S[u4 * 4 + 2], qv.z, r);
      r = fmaf(S[u4 * 4 + 3], qv.w, r);
    }
    r += __shfl_xor(r, 1);
    r += __shfl_xor(r, 2);
    if ((tid & 3) == 0) {
      size_t gi = ((size_t)(b * 1024 + t0 + t) * 8 + h) * 64 + i;
      AB[gi] = f2b(RP[gi] + p * r);
    }
  }
}

// ---------------------------------------------------------------------------
extern "C" void kernel_launch(void* const* d_in, const int* in_sizes, int n_in,
                              void* d_out, int out_size, void* d_ws, size_t ws_size,
                              hipStream_t stream) {
  const float* x = (const float*)d_in[0];
  const float* bmin = (const float*)d_in[1];
  const float* bmax = (const float*)d_in[2];
  const float* motif = (const float*)d_in[3];
  const float* Wk = (const float*)d_in[4];
  const float* bk = (const float*)d_in[5];
  const float* Wq = (const float*)d_in[6];
  const float* bq = (const float*)d_in[7];
  const float* Wv = (const float*)d_in[8];
  const float* bv = (const float*)d_in[9];
  const float* Wo = (const float*)d_in[10];
  const float* bo = (const float*)d_in[11];
  const float* Wd = (const float*)d_in[12];
  const float* bd = (const float*)d_in[13];
  const float* Wgw = (const float*)d_in[14];
  const float* bgw = (const float*)d_in[15];
  const float* Wgf = (const float*)d_in[16];
  const float* bgf = (const float*)d_in[17];
  const float* Wps = (const float*)d_in[18];
  const float* bps = (const float*)d_in[19];
  const float* ln1g = (const float*)d_in[20];
  const float* ln1b = (const float*)d_in[21];
  const float* ln2g = (const float*)d_in[22];
  const float* ln2b = (const float*)d_in[23];
  const float* W1 = (const float*)d_in[24];
  const float* b1 = (const float*)d_in[25];
  const float* W2 = (const float*)d_in[26];
  const float* b2 = (const float*)d_in[27];

  char* ws = (char*)d_ws;
  u16* WTQ = (u16*)(ws + 0);             // 1664x512 bf16 -> 1703936
  u16* WTO = (u16*)(ws + 1703936);       // -> 2228224
  u16* WT1 = (u16*)(ws + 2228224);       // -> 4325376
  u16* WT2 = (u16*)(ws + 4325376);       // -> 6422528
  u16* WTPS = (u16*)(ws + 6422528);      // -> 6946816
  float* BQV = (float*)(ws + 6946816);   // -> 6953472
  u16* XN = (u16*)(ws + 6953984);        // -> 9051136
  float* G0 = (float*)(ws + 9051136);    // 2048x128 f32 -> 10099712
  u16* KB = (u16*)(ws + 10099712);       // -> 12196864
  u16* QB = (u16*)(ws + 12196864);       // -> 14294016
  u16* VB = (u16*)(ws + 14294016);       // -> 16391168
  float* DEC = (float*)(ws + 16391168);  // -> 16456704
  float* LC = (float*)(ws + 16456704);   // -> 16522240
  float* WW = (float*)(ws + 16522240);   // -> 16587776
  float* SVG = (float*)(ws + 16587776);  // -> 16653312
  float* RP = (float*)(ws + 16653312);   // 4MB -> 20847616
  float* SF = (float*)(ws + 20847616);   // 8MB -> 29236224
  float* SI = (float*)(ws + 29236224);   // 8MB -> 37624832
  u16* AB = (u16*)(ws + 37624832);       // 2MB -> 39721984
  float* X2 = (float*)(ws + 39721984);   // 4MB -> 43916288
  u16* HB = (u16*)(ws + 43916288);       // 2MB -> 46013440
  u16* MID = (u16*)(ws + 9051136);       // 8MB -> 17439744 (G0..SVG,RP-head dead at FFN1)
  u16* X3B = (u16*)(ws + 20847616);      // 2MB (SF dead at FFN2)

  float* out0 = (float*)d_out;
  float* out1 = out0 + 1048576;
  float* out2 = out0 + 1114112;
  float* out3 = out0 + 2162688;

  prep_weights<<<5440, 256, 0, stream>>>(Wk, Wq, Wv, Wo, Wps, W1, W2, Wd, Wgw, Wgf,
                                         bk, bq, bv, bd, bgw, bgf, x, ln1g, ln1b,
                                         WTQ, WTO, WTPS, WT1, WT2, BQV, XN);
  gemm2s<64, 5><<<dim3(26, 32), 256, 0, stream>>>(XN, WTQ, BQV, G0, nullptr, KB, QB, VB,
                                                  nullptr, nullptr, 2048, 1664, 512);
  gates_logcum<<<16, 256, 0, stream>>>(G0, DEC, SVG, LC, WW);
  scan_phase1<<<dim3(32, 8, 2), 256, 0, stream>>>(KB, QB, VB, DEC, WW, SVG, RP, SF);
  scan_phase2p<<<256, 256, 0, stream>>>(SF, LC, SI, out1);
  scan_phase3<<<dim3(32, 8, 2), 256, 0, stream>>>(QB, SI, LC, RP, AB);

  gemm2s<32, 1><<<dim3(8, 64), 256, 0, stream>>>(AB, WTO, bo, X2, nullptr, nullptr,
                                                 nullptr, nullptr, x, motif, 2048, 512, 512);
  ln_f32<<<2048, 256, 0, stream>>>(X2, ln2g, ln2b, HB);
  gemm2s<64, 2><<<dim3(32, 32), 256, 0, stream>>>(HB, WT1, b1, nullptr, nullptr, MID,
                                                  nullptr, nullptr, nullptr, nullptr,
                                                  2048, 2048, 512);
  gemm2s<32, 3><<<dim3(8, 64), 256, 0, stream>>>(MID, WT2, b2, out0, nullptr, X3B,
                                                 nullptr, nullptr, X2, nullptr,
                                                 2048, 512, 2048);
  gemm2s<32, 4><<<dim3(8, 64), 256, 0, stream>>>(X3B, WTPS, bps, out2, out3, nullptr,
                                                 nullptr, nullptr, bmin, bmax,
                                                 2048, 512, 512);
}